// Round 1
// baseline (1119.495 us; speedup 1.0000x reference)
//
#include <hip/hip_runtime.h>

#define NN 50000
#define NE 800000
#define NT (NE + NN)   /* 850000 edges incl self-loops */
#define NG 64

__device__ __forceinline__ unsigned fenc(float f) {
  unsigned b = __float_as_uint(f);
  return (b & 0x80000000u) ? ~b : (b | 0x80000000u);
}
__device__ __forceinline__ float fdec(unsigned k) {
  return __uint_as_float((k & 0x80000000u) ? (k & 0x7fffffffu) : ~k);
}
__device__ __forceinline__ float leaky(float v) { return v > 0.f ? v : 0.2f * v; }

// ---------------- conv1: edge logits (wave per edge, grid-stride) ----------------
__global__ void k_edge1(const float* __restrict__ x, const int* __restrict__ ei,
                        const float* __restrict__ Wl1, const float* __restrict__ bl1,
                        const float* __restrict__ Wr1, const float* __restrict__ br1,
                        const float* __restrict__ att1,
                        float* __restrict__ logits1, unsigned* __restrict__ m1) {
  __shared__ float swl[512], swr[512], sb[256], satt[256];
  for (int i = threadIdx.x; i < 512; i += 256) { swl[i] = Wl1[i]; swr[i] = Wr1[i]; }
  if (threadIdx.x < 256) { sb[threadIdx.x] = bl1[threadIdx.x] + br1[threadIdx.x];
                           satt[threadIdx.x] = att1[threadIdx.x]; }
  __syncthreads();
  const float2* x2 = (const float2*)x;
  int lane = threadIdx.x & 63;
  int wid = (blockIdx.x * blockDim.x + threadIdx.x) >> 6;
  int nw = (gridDim.x * blockDim.x) >> 6;
  for (int e = wid; e < NT; e += nw) {
    int src, dst;
    if (e < NE) { src = ei[e]; dst = ei[NE + e]; } else { src = dst = e - NE; }
    float2 xs = x2[src], xd = x2[dst];
    float lg[4];
#pragma unroll
    for (int h = 0; h < 4; h++) {
      int ch = h * 64 + lane;
      float v = swl[ch*2] * xs.x + swl[ch*2+1] * xs.y
              + swr[ch*2] * xd.x + swr[ch*2+1] * xd.y + sb[ch];
      lg[h] = leaky(v) * satt[ch];
    }
#pragma unroll
    for (int off = 32; off >= 1; off >>= 1) {
#pragma unroll
      for (int h = 0; h < 4; h++) lg[h] += __shfl_xor(lg[h], off, 64);
    }
    if (lane < 4) {
      float l = lg[lane];
      logits1[e*4 + lane] = l;
      atomicMax(&m1[dst*4 + lane], fenc(l));
    }
  }
}

// conv1: exp + denom (thread per edge-head)
__global__ void k_e1exp(const int* __restrict__ ei, float* __restrict__ logits1,
                        const unsigned* __restrict__ m1, float* __restrict__ d1) {
  int idx = blockIdx.x * 256 + threadIdx.x;
  if (idx >= NT * 4) return;
  int e = idx >> 2, h = idx & 3;
  int dst = (e < NE) ? ei[NE + e] : e - NE;
  float ex = __expf(logits1[idx] - fdec(m1[dst*4 + h]));
  logits1[idx] = ex;
  atomicAdd(&d1[dst*4 + h], ex);
}

// conv1: weighted x aggregation (thread per edge-head) -> s1[N][4][2]
__global__ void k_e1agg(const float* __restrict__ x, const int* __restrict__ ei,
                        const float* __restrict__ logits1, const float* __restrict__ d1,
                        float* __restrict__ s1) {
  int idx = blockIdx.x * 256 + threadIdx.x;
  if (idx >= NT * 4) return;
  int e = idx >> 2, h = idx & 3;
  int src, dst;
  if (e < NE) { src = ei[e]; dst = ei[NE + e]; } else { src = dst = e - NE; }
  float alpha = logits1[idx] / d1[dst*4 + h];
  const float2* x2 = (const float2*)x;
  float2 xs = x2[src];
  atomicAdd(&s1[(dst*4 + h)*2 + 0], alpha * xs.x);
  atomicAdd(&s1[(dst*4 + h)*2 + 1], alpha * xs.y);
}

// fused node kernel: s1 -> t=relu(Wl1*s+bl1+bias1) -> xl2,xr2   (16 nodes/block)
__global__ void k_node1(const float* __restrict__ s1,
                        const float* __restrict__ Wl1, const float* __restrict__ bl1,
                        const float* __restrict__ bias1,
                        const float* __restrict__ Wl2, const float* __restrict__ bl2,
                        const float* __restrict__ Wr2, const float* __restrict__ br2,
                        float* __restrict__ xl2, float* __restrict__ xr2) {
  __shared__ float t[16][256];
  int tid = threadIdx.x;
  int base = blockIdx.x * 16;
  int h = tid >> 6;
  float w0 = Wl1[tid*2], w1 = Wl1[tid*2+1], bb = bl1[tid] + bias1[tid];
  for (int i = 0; i < 16; i++) {
    int node = base + i;
    float s0 = s1[node*8 + h*2], sv = s1[node*8 + h*2 + 1];
    float v = w0 * s0 + w1 * sv + bb;
    t[i][tid] = v > 0.f ? v : 0.f;
  }
  __syncthreads();
  int ch = tid & 127;
  int grp = tid >> 7;
  const float* W = (ch < 64) ? (Wl2 + ch*256) : (Wr2 + (ch-64)*256);
  float bias = (ch < 64) ? bl2[ch] : br2[ch-64];
  float acc[8];
#pragma unroll
  for (int n = 0; n < 8; n++) acc[n] = bias;
  for (int k = 0; k < 256; k += 4) {
    float4 w4 = *(const float4*)(W + k);
#pragma unroll
    for (int n = 0; n < 8; n++) {
      const float* tp = &t[grp*8 + n][k];
      acc[n] += w4.x*tp[0] + w4.y*tp[1] + w4.z*tp[2] + w4.w*tp[3];
    }
  }
#pragma unroll
  for (int n = 0; n < 8; n++) {
    int node = base + grp*8 + n;
    if (ch < 64) xl2[node*64 + ch] = acc[n];
    else         xr2[node*64 + (ch - 64)] = acc[n];
  }
}

// conv2: edge logits (wave per edge)
__global__ void k_edge2(const float* __restrict__ xl2, const float* __restrict__ xr2,
                        const int* __restrict__ ei, const float* __restrict__ att2,
                        float* __restrict__ logit2, unsigned* __restrict__ m2) {
  int lane = threadIdx.x & 63;
  int e = blockIdx.x * 4 + (threadIdx.x >> 6);
  if (e >= NT) return;
  int src, dst;
  if (e < NE) { src = ei[e]; dst = ei[NE + e]; } else { src = dst = e - NE; }
  float v = leaky(xl2[src*64 + lane] + xr2[dst*64 + lane]) * att2[lane];
#pragma unroll
  for (int off = 32; off >= 1; off >>= 1) v += __shfl_xor(v, off, 64);
  if (lane == 0) {
    logit2[e] = v;
    atomicMax(&m2[dst], fenc(v));
  }
}

// conv2: exp + denom (thread per edge)
__global__ void k_e2exp(const int* __restrict__ ei, float* __restrict__ logit2,
                        const unsigned* __restrict__ m2, float* __restrict__ d2) {
  int e = blockIdx.x * 256 + threadIdx.x;
  if (e >= NT) return;
  int dst = (e < NE) ? ei[NE + e] : e - NE;
  float ex = __expf(logit2[e] - fdec(m2[dst]));
  logit2[e] = ex;
  atomicAdd(&d2[dst], ex);
}

// conv2: aggregation (wave per edge, lane-parallel atomics)
__global__ void k_e2agg(const float* __restrict__ xl2, const int* __restrict__ ei,
                        const float* __restrict__ logit2, const float* __restrict__ d2,
                        float* __restrict__ out2) {
  int lane = threadIdx.x & 63;
  int e = blockIdx.x * 4 + (threadIdx.x >> 6);
  if (e >= NT) return;
  int src, dst;
  if (e < NE) { src = ei[e]; dst = ei[NE + e]; } else { src = dst = e - NE; }
  float alpha = logit2[e] / d2[dst];
  atomicAdd(&out2[dst*64 + lane], alpha * xl2[src*64 + lane]);
}

// pooling: wave per 32 contiguous nodes, run-length flush (batch is sorted)
__global__ void k_pool(const float* __restrict__ out2, const int* __restrict__ batch,
                       float* __restrict__ pool, float* __restrict__ counts) {
  int lane = threadIdx.x & 63;
  int wid = blockIdx.x * 4 + (threadIdx.x >> 6);
  int start = wid * 32;
  if (start >= NN) return;
  int end = start + 32; if (end > NN) end = NN;
  int cur = batch[start];
  float acc = 0.f; int cnt = 0;
  for (int node = start; node < end; node++) {
    int b = batch[node];
    if (b != cur) {
      atomicAdd(&pool[cur*64 + lane], acc);
      if (lane == 0) atomicAdd(&counts[cur], (float)cnt);
      acc = 0.f; cnt = 0; cur = b;
    }
    acc += out2[node*64 + lane];
    cnt++;
  }
  atomicAdd(&pool[cur*64 + lane], acc);
  if (lane == 0) atomicAdd(&counts[cur], (float)cnt);
}

// final: mean, +bias2, concat baseline_k, MLP 65->32->16->1, out = bk + c
__global__ void k_final(const float* __restrict__ pool, const float* __restrict__ counts,
                        const float* __restrict__ bias2, const float* __restrict__ bk,
                        const float* __restrict__ wc1, const float* __restrict__ bc1,
                        const float* __restrict__ wc2, const float* __restrict__ bc2,
                        const float* __restrict__ wc3, const float* __restrict__ bc3,
                        float* __restrict__ out) {
  int g = threadIdx.x;
  if (g >= NG) return;
  float cnt = counts[g]; cnt = cnt > 1.f ? cnt : 1.f;
  float ge[64];
#pragma unroll
  for (int c = 0; c < 64; c++) ge[c] = pool[g*64 + c] / cnt + bias2[c];
  float b = bk[g];
  float c1[32];
#pragma unroll
  for (int o = 0; o < 32; o++) {
    float a = bc1[o];
    for (int k = 0; k < 64; k++) a += wc1[o*65 + k] * ge[k];
    a += wc1[o*65 + 64] * b;
    c1[o] = a > 0.f ? a : 0.f;
  }
  float c2[16];
#pragma unroll
  for (int o = 0; o < 16; o++) {
    float a = bc2[o];
    for (int k = 0; k < 32; k++) a += wc2[o*32 + k] * c1[k];
    c2[o] = a > 0.f ? a : 0.f;
  }
  float a = bc3[0];
  for (int k = 0; k < 16; k++) a += wc3[k] * c2[k];
  out[g] = b + a;
}

extern "C" void kernel_launch(void* const* d_in, const int* in_sizes, int n_in,
                              void* d_out, int out_size, void* d_ws, size_t ws_size,
                              hipStream_t stream) {
  (void)in_sizes; (void)n_in; (void)out_size; (void)ws_size;
  const float* x     = (const float*)d_in[0];
  const int*   ei    = (const int*)d_in[1];
  const int*   batch = (const int*)d_in[2];
  const float* bk    = (const float*)d_in[3];
  const float* Wl1   = (const float*)d_in[4];
  const float* bl1   = (const float*)d_in[5];
  const float* Wr1   = (const float*)d_in[6];
  const float* br1   = (const float*)d_in[7];
  const float* att1  = (const float*)d_in[8];
  const float* bias1 = (const float*)d_in[9];
  const float* Wl2   = (const float*)d_in[10];
  const float* bl2   = (const float*)d_in[11];
  const float* Wr2   = (const float*)d_in[12];
  const float* br2   = (const float*)d_in[13];
  const float* att2  = (const float*)d_in[14];
  const float* bias2 = (const float*)d_in[15];
  const float* wc1   = (const float*)d_in[16];
  const float* bc1   = (const float*)d_in[17];
  const float* wc2   = (const float*)d_in[18];
  const float* bc2   = (const float*)d_in[19];
  const float* wc3   = (const float*)d_in[20];
  const float* bc3   = (const float*)d_in[21];
  float* out = (float*)d_out;

  float* ws = (float*)d_ws;
  // workspace layout (element offsets, floats)
  unsigned* m1    = (unsigned*)(ws + 0);   // [N*4]        200000
  float*    d1    = ws + 200000;           // [N*4]        200000
  float*    s1    = ws + 400000;           // [N*4*2]      400000
  // --- zero region 1: [0, 800000)
  unsigned* m2    = (unsigned*)(ws + 800000); // [N]       50048 (padded)
  float*    d2    = ws + 850048;           // [N]          50048
  float*    out2  = ws + 900096;           // [N*64]       3200000
  float*    pool  = ws + 4100096;          // [G*64]       4096
  float*    cnts  = ws + 4104192;          // [G]          64
  // --- zero region 2: [800000, 4104256)
  float*    logits1 = ws + 4104256;        // [NT*4]       3400000
  float*    logit2  = ws + 7504256;        // [NT]         850048
  float*    xl2     = ws + 8354304;        // [N*64]       3200000
  float*    xr2     = ws + 11554304;       // [N*64]       3200000

  hipMemsetAsync(ws, 0, 800000 * sizeof(float), stream);
  hipMemsetAsync(ws + 800000, 0, 3304256 * sizeof(float), stream);

  // conv1
  k_edge1<<<2048, 256, 0, stream>>>(x, ei, Wl1, bl1, Wr1, br1, att1, logits1, m1);
  int eh_blocks = (NT * 4 + 255) / 256;
  k_e1exp<<<eh_blocks, 256, 0, stream>>>(ei, logits1, m1, d1);
  k_e1agg<<<eh_blocks, 256, 0, stream>>>(x, ei, logits1, d1, s1);
  k_node1<<<NN / 16, 256, 0, stream>>>(s1, Wl1, bl1, bias1, Wl2, bl2, Wr2, br2, xl2, xr2);

  // conv2
  int ew_blocks = (NT + 3) / 4;
  k_edge2<<<ew_blocks, 256, 0, stream>>>(xl2, xr2, ei, att2, logit2, m2);
  k_e2exp<<<(NT + 255) / 256, 256, 0, stream>>>(ei, logit2, m2, d2);
  k_e2agg<<<ew_blocks, 256, 0, stream>>>(xl2, ei, logit2, d2, out2);

  // pool + MLP
  k_pool<<<(((NN + 31) / 32) + 3) / 4, 256, 0, stream>>>(out2, batch, pool, cnts);
  k_final<<<1, 64, 0, stream>>>(pool, cnts, bias2, bk, wc1, bc1, wc2, bc2, wc3, bc3, out);
}

// Round 2
// 671.857 us; speedup vs baseline: 1.6663x; 1.6663x over previous
//
#include <hip/hip_runtime.h>

#define NN 50000
#define NE 800000
#define NT (NE + NN)   /* 850000 edges incl self-loops */
#define NG 64

__device__ __forceinline__ float leaky(float v) { return v > 0.f ? v : 0.2f * v; }

// ---------------- conv1: edge exp(logits) + denom; 16 lanes per edge ----------------
__global__ __launch_bounds__(256) void k_edge1(
    const float* __restrict__ x, const int* __restrict__ ei,
    const float* __restrict__ Wl1, const float* __restrict__ bl1,
    const float* __restrict__ Wr1, const float* __restrict__ br1,
    const float* __restrict__ att1,
    float* __restrict__ ex1, float* __restrict__ d1) {
  int tid = blockIdx.x * 256 + threadIdx.x;
  int sub = threadIdx.x & 15;
  int gid = tid >> 4;
  int ng = (gridDim.x * 256) >> 4;
  // preload this lane's 16 channels of weights: ch = h*64 + sub*4 + c
  float4 w[4][4];
  float bb[4][4], at[4][4];
#pragma unroll
  for (int h = 0; h < 4; h++)
#pragma unroll
    for (int c = 0; c < 4; c++) {
      int ch = h * 64 + sub * 4 + c;
      w[h][c] = make_float4(Wl1[ch*2], Wl1[ch*2+1], Wr1[ch*2], Wr1[ch*2+1]);
      bb[h][c] = bl1[ch] + br1[ch];
      at[h][c] = att1[ch];
    }
  const float2* x2 = (const float2*)x;
  for (int e = gid; e < NT; e += ng) {
    int src, dst;
    if (e < NE) { src = ei[e]; dst = ei[NE + e]; } else { src = dst = e - NE; }
    float2 xs = x2[src], xd = x2[dst];
    float lg[4];
#pragma unroll
    for (int h = 0; h < 4; h++) {
      float a = 0.f;
#pragma unroll
      for (int c = 0; c < 4; c++) {
        float v = w[h][c].x * xs.x + w[h][c].y * xs.y
                + w[h][c].z * xd.x + w[h][c].w * xd.y + bb[h][c];
        a += at[h][c] * leaky(v);
      }
      lg[h] = a;
    }
    // reduce-scatter over sub bits 0-1, then butterfly over bits 2-3
    float t0 = __shfl_xor(lg[0], 1), t1 = __shfl_xor(lg[1], 1);
    float t2 = __shfl_xor(lg[2], 1), t3 = __shfl_xor(lg[3], 1);
    float a0, a1;
    if (sub & 1) { a0 = lg[2] + t2; a1 = lg[3] + t3; }
    else         { a0 = lg[0] + t0; a1 = lg[1] + t1; }
    float u0 = __shfl_xor(a0, 2), u1 = __shfl_xor(a1, 2);
    float b = (sub & 2) ? (a1 + u1) : (a0 + u0);
    b += __shfl_xor(b, 4);
    b += __shfl_xor(b, 8);
    if (sub < 4) {
      int h = ((sub & 1) << 1) | ((sub >> 1) & 1);
      float exv = __expf(b);           // no max-subtraction: logits bounded small
      ex1[e*4 + h] = exv;
      atomicAdd(&d1[dst*4 + h], exv);
    }
  }
}

// conv1: weighted x aggregation (thread per edge-head) -> s1[N][4][2]
__global__ void k_e1agg(const float* __restrict__ x, const int* __restrict__ ei,
                        const float* __restrict__ ex1, const float* __restrict__ d1,
                        float* __restrict__ s1) {
  int idx = blockIdx.x * 256 + threadIdx.x;
  if (idx >= NT * 4) return;
  int e = idx >> 2, h = idx & 3;
  int src, dst;
  if (e < NE) { src = ei[e]; dst = ei[NE + e]; } else { src = dst = e - NE; }
  float alpha = ex1[idx] / d1[dst*4 + h];
  const float2* x2 = (const float2*)x;
  float2 xs = x2[src];
  atomicAdd(&s1[(dst*4 + h)*2 + 0], alpha * xs.x);
  atomicAdd(&s1[(dst*4 + h)*2 + 1], alpha * xs.y);
}

// fused node kernel: s1 -> t=relu(Wl1*s+bl1+bias1) -> xl2,xr2   (16 nodes/block)
__global__ void k_node1(const float* __restrict__ s1,
                        const float* __restrict__ Wl1, const float* __restrict__ bl1,
                        const float* __restrict__ bias1,
                        const float* __restrict__ Wl2, const float* __restrict__ bl2,
                        const float* __restrict__ Wr2, const float* __restrict__ br2,
                        float* __restrict__ xl2, float* __restrict__ xr2) {
  __shared__ float t[16][256];
  int tid = threadIdx.x;
  int base = blockIdx.x * 16;
  int h = tid >> 6;
  float w0 = Wl1[tid*2], w1 = Wl1[tid*2+1], bb = bl1[tid] + bias1[tid];
  for (int i = 0; i < 16; i++) {
    int node = base + i;
    float s0 = s1[node*8 + h*2], sv = s1[node*8 + h*2 + 1];
    float v = w0 * s0 + w1 * sv + bb;
    t[i][tid] = v > 0.f ? v : 0.f;
  }
  __syncthreads();
  int ch = tid & 127;
  int grp = tid >> 7;
  const float* W = (ch < 64) ? (Wl2 + ch*256) : (Wr2 + (ch-64)*256);
  float bias = (ch < 64) ? bl2[ch] : br2[ch-64];
  float acc[8];
#pragma unroll
  for (int n = 0; n < 8; n++) acc[n] = bias;
  for (int k = 0; k < 256; k += 4) {
    float4 w4 = *(const float4*)(W + k);
#pragma unroll
    for (int n = 0; n < 8; n++) {
      const float* tp = &t[grp*8 + n][k];
      acc[n] += w4.x*tp[0] + w4.y*tp[1] + w4.z*tp[2] + w4.w*tp[3];
    }
  }
#pragma unroll
  for (int n = 0; n < 8; n++) {
    int node = base + grp*8 + n;
    if (ch < 64) xl2[node*64 + ch] = acc[n];
    else         xr2[node*64 + (ch - 64)] = acc[n];
  }
}

// conv2: edge exp(logit) + denom (wave per edge)
__global__ void k_edge2(const float* __restrict__ xl2, const float* __restrict__ xr2,
                        const int* __restrict__ ei, const float* __restrict__ att2,
                        float* __restrict__ ex2, float* __restrict__ d2) {
  int lane = threadIdx.x & 63;
  int e = blockIdx.x * 4 + (threadIdx.x >> 6);
  if (e >= NT) return;
  int src, dst;
  if (e < NE) { src = ei[e]; dst = ei[NE + e]; } else { src = dst = e - NE; }
  float v = leaky(xl2[src*64 + lane] + xr2[dst*64 + lane]) * att2[lane];
#pragma unroll
  for (int off = 32; off >= 1; off >>= 1) v += __shfl_xor(v, off, 64);
  if (lane == 0) {
    float exv = __expf(v);
    ex2[e] = exv;
    atomicAdd(&d2[dst], exv);
  }
}

// conv2: aggregation (wave per edge, lane-parallel atomics)
__global__ void k_e2agg(const float* __restrict__ xl2, const int* __restrict__ ei,
                        const float* __restrict__ ex2, const float* __restrict__ d2,
                        float* __restrict__ out2) {
  int lane = threadIdx.x & 63;
  int e = blockIdx.x * 4 + (threadIdx.x >> 6);
  if (e >= NT) return;
  int src, dst;
  if (e < NE) { src = ei[e]; dst = ei[NE + e]; } else { src = dst = e - NE; }
  float alpha = ex2[e] / d2[dst];
  atomicAdd(&out2[dst*64 + lane], alpha * xl2[src*64 + lane]);
}

// pooling: wave per 32 contiguous nodes, run-length flush (batch is sorted)
__global__ void k_pool(const float* __restrict__ out2, const int* __restrict__ batch,
                       float* __restrict__ pool, float* __restrict__ counts) {
  int lane = threadIdx.x & 63;
  int wid = blockIdx.x * 4 + (threadIdx.x >> 6);
  int start = wid * 32;
  if (start >= NN) return;
  int end = start + 32; if (end > NN) end = NN;
  int cur = batch[start];
  float acc = 0.f; int cnt = 0;
  for (int node = start; node < end; node++) {
    int b = batch[node];
    if (b != cur) {
      atomicAdd(&pool[cur*64 + lane], acc);
      if (lane == 0) atomicAdd(&counts[cur], (float)cnt);
      acc = 0.f; cnt = 0; cur = b;
    }
    acc += out2[node*64 + lane];
    cnt++;
  }
  atomicAdd(&pool[cur*64 + lane], acc);
  if (lane == 0) atomicAdd(&counts[cur], (float)cnt);
}

// final: mean, +bias2, concat baseline_k, MLP 65->32->16->1, out = bk + c
// one block per graph; activations in LDS (runtime-indexable, no scratch spill)
__global__ void k_final(const float* __restrict__ pool, const float* __restrict__ counts,
                        const float* __restrict__ bias2, const float* __restrict__ bk,
                        const float* __restrict__ wc1, const float* __restrict__ bc1,
                        const float* __restrict__ wc2, const float* __restrict__ bc2,
                        const float* __restrict__ wc3, const float* __restrict__ bc3,
                        float* __restrict__ out) {
  __shared__ float sge[65], sc1[32], sc2[16];
  int g = blockIdx.x, t = threadIdx.x;
  if (t < 64) {
    float cnt = counts[g]; cnt = cnt > 1.f ? cnt : 1.f;
    sge[t] = pool[g*64 + t] / cnt + bias2[t];
  }
  if (t == 0) sge[64] = bk[g];
  __syncthreads();
  if (t < 32) {
    float a = bc1[t];
    for (int k = 0; k < 65; k++) a += wc1[t*65 + k] * sge[k];
    sc1[t] = a > 0.f ? a : 0.f;
  }
  __syncthreads();
  if (t < 16) {
    float a = bc2[t];
    for (int k = 0; k < 32; k++) a += wc2[t*32 + k] * sc1[k];
    sc2[t] = a > 0.f ? a : 0.f;
  }
  __syncthreads();
  if (t == 0) {
    float a = bc3[0];
    for (int k = 0; k < 16; k++) a += wc3[k] * sc2[k];
    out[g] = bk[g] + a;
  }
}

extern "C" void kernel_launch(void* const* d_in, const int* in_sizes, int n_in,
                              void* d_out, int out_size, void* d_ws, size_t ws_size,
                              hipStream_t stream) {
  (void)in_sizes; (void)n_in; (void)out_size; (void)ws_size;
  const float* x     = (const float*)d_in[0];
  const int*   ei    = (const int*)d_in[1];
  const int*   batch = (const int*)d_in[2];
  const float* bk    = (const float*)d_in[3];
  const float* Wl1   = (const float*)d_in[4];
  const float* bl1   = (const float*)d_in[5];
  const float* Wr1   = (const float*)d_in[6];
  const float* br1   = (const float*)d_in[7];
  const float* att1  = (const float*)d_in[8];
  const float* bias1 = (const float*)d_in[9];
  const float* Wl2   = (const float*)d_in[10];
  const float* bl2   = (const float*)d_in[11];
  const float* Wr2   = (const float*)d_in[12];
  const float* br2   = (const float*)d_in[13];
  const float* att2  = (const float*)d_in[14];
  const float* bias2 = (const float*)d_in[15];
  const float* wc1   = (const float*)d_in[16];
  const float* bc1   = (const float*)d_in[17];
  const float* wc2   = (const float*)d_in[18];
  const float* bc2   = (const float*)d_in[19];
  const float* wc3   = (const float*)d_in[20];
  const float* bc3   = (const float*)d_in[21];
  float* out = (float*)d_out;

  float* ws = (float*)d_ws;
  // ---- zeroed region (one memset): [0, 3854208) floats ----
  float* d1   = ws + 0;        // [N*4]     200000
  float* s1   = ws + 200000;   // [N*4*2]   400000
  float* d2   = ws + 600000;   // [N]       50048 (padded)
  float* out2 = ws + 650048;   // [N*64]    3200000
  float* pool = ws + 3850048;  // [G*64]    4096
  float* cnts = ws + 3854144;  // [G]       64
  // ---- write-before-read region ----
  float* ex1   = ws + 3854208; // [NT*4]    3400000
  float* ex2   = ws + 7254208; // [NT]      850000
  float* xl2   = ws + 8104208; // [N*64]    3200000
  float* xr2   = ws + 11304208;// [N*64]    3200000

  hipMemsetAsync(ws, 0, 3854208 * sizeof(float), stream);

  // conv1
  k_edge1<<<2048, 256, 0, stream>>>(x, ei, Wl1, bl1, Wr1, br1, att1, ex1, d1);
  int eh_blocks = (NT * 4 + 255) / 256;
  k_e1agg<<<eh_blocks, 256, 0, stream>>>(x, ei, ex1, d1, s1);
  k_node1<<<NN / 16, 256, 0, stream>>>(s1, Wl1, bl1, bias1, Wl2, bl2, Wr2, br2, xl2, xr2);

  // conv2
  int ew_blocks = (NT + 3) / 4;
  k_edge2<<<ew_blocks, 256, 0, stream>>>(xl2, xr2, ei, att2, ex2, d2);
  k_e2agg<<<ew_blocks, 256, 0, stream>>>(xl2, ei, ex2, d2, out2);

  // pool + MLP
  k_pool<<<(((NN + 31) / 32) + 3) / 4, 256, 0, stream>>>(out2, batch, pool, cnts);
  k_final<<<NG, 64, 0, stream>>>(pool, cnts, bias2, bk, wc1, bc1, wc2, bc2, wc3, bc3, out);
}

// Round 3
// 519.624 us; speedup vs baseline: 2.1544x; 1.2930x over previous
//
#include <hip/hip_runtime.h>

#define NN 50000
#define NE 800000
#define NT (NE + NN)   /* 850000 edges incl self-loops */
#define NG 64

__device__ __forceinline__ float leaky(float v) { return v > 0.f ? v : 0.2f * v; }

// ---------- CSR build ----------
__global__ void k_hist(const int* __restrict__ ei, int* __restrict__ deg) {
  int e = blockIdx.x * 256 + threadIdx.x;
  if (e >= NT) return;
  int dst = (e < NE) ? ei[NE + e] : e - NE;
  atomicAdd(&deg[dst], 1);
}

__global__ __launch_bounds__(1024) void k_scan(const int* __restrict__ deg,
                                               int* __restrict__ rowptr,
                                               int* __restrict__ cursor) {
  __shared__ int part[1024];
  int t = threadIdx.x;
  const int CH = (NN + 1023) / 1024;  // 49
  int base = t * CH;
  int s = 0;
  for (int i = 0; i < CH; i++) {
    int idx = base + i;
    if (idx < NN) s += deg[idx];
  }
  part[t] = s;
  __syncthreads();
  for (int off = 1; off < 1024; off <<= 1) {
    int v = (t >= off) ? part[t - off] : 0;
    __syncthreads();
    part[t] += v;
    __syncthreads();
  }
  int run = (t == 0) ? 0 : part[t - 1];
  for (int i = 0; i < CH; i++) {
    int idx = base + i;
    if (idx < NN) {
      rowptr[idx] = run;
      cursor[idx] = run;
      run += deg[idx];
    }
  }
  if (t == 1023) rowptr[NN] = run;  // == NT
}

__global__ void k_scatter(const int* __restrict__ ei, int* __restrict__ cursor,
                          int* __restrict__ csr_src) {
  int e = blockIdx.x * 256 + threadIdx.x;
  if (e >= NT) return;
  int src, dst;
  if (e < NE) { src = ei[e]; dst = ei[NE + e]; } else { src = dst = e - NE; }
  int pos = atomicAdd(&cursor[dst], 1);
  csr_src[pos] = src;
}

// ---------- conv1: fused logits+softmax+agg, wave per dst node ----------
// 4 edges in flight (one per 16-lane group); lane handles 16 channels (4 heads x 4)
__global__ __launch_bounds__(256) void k_conv1(
    const float* __restrict__ x, const int* __restrict__ rowptr,
    const int* __restrict__ csr_src,
    const float* __restrict__ Wl1, const float* __restrict__ bl1,
    const float* __restrict__ Wr1, const float* __restrict__ br1,
    const float* __restrict__ att1, float* __restrict__ s1) {
  int lane = threadIdx.x & 63;
  int node = blockIdx.x * 4 + (threadIdx.x >> 6);
  if (node >= NN) return;
  int sub = lane & 15, grp = lane >> 4;
  const float2* x2 = (const float2*)x;
  float2 xd = x2[node];
  float wl0[4][4], wl1r[4][4], r[4][4], at[4][4];
#pragma unroll
  for (int h = 0; h < 4; h++)
#pragma unroll
    for (int k = 0; k < 4; k++) {
      int ch = h * 64 + sub * 4 + k;
      wl0[h][k] = Wl1[ch * 2];
      wl1r[h][k] = Wl1[ch * 2 + 1];
      r[h][k] = Wr1[ch * 2] * xd.x + Wr1[ch * 2 + 1] * xd.y + bl1[ch] + br1[ch];
      at[h][k] = att1[ch];
    }
  float ax[4] = {0, 0, 0, 0}, ay[4] = {0, 0, 0, 0}, ad[4] = {0, 0, 0, 0};
  int start = rowptr[node], end = rowptr[node + 1];
  for (int j = start; j < end; j += 4) {
    int e = j + grp;
    bool valid = e < end;
    int src = valid ? csr_src[e] : node;
    float2 xs = x2[src];
    float p[4];
#pragma unroll
    for (int h = 0; h < 4; h++) {
      float a = 0.f;
#pragma unroll
      for (int k = 0; k < 4; k++) {
        float v = wl0[h][k] * xs.x + wl1r[h][k] * xs.y + r[h][k];
        a += at[h][k] * leaky(v);
      }
      p[h] = a;
    }
#pragma unroll
    for (int off = 1; off <= 8; off <<= 1) {
#pragma unroll
      for (int h = 0; h < 4; h++) p[h] += __shfl_xor(p[h], off, 64);
    }
#pragma unroll
    for (int h = 0; h < 4; h++) {
      float exv = valid ? __expf(p[h]) : 0.f;
      ax[h] += exv * xs.x;
      ay[h] += exv * xs.y;
      ad[h] += exv;
    }
  }
#pragma unroll
  for (int off = 16; off <= 32; off <<= 1) {
#pragma unroll
    for (int h = 0; h < 4; h++) {
      ax[h] += __shfl_xor(ax[h], off, 64);
      ay[h] += __shfl_xor(ay[h], off, 64);
      ad[h] += __shfl_xor(ad[h], off, 64);
    }
  }
  if (lane == 0) {
#pragma unroll
    for (int h = 0; h < 4; h++) {
      s1[node * 8 + h * 2 + 0] = ax[h] / ad[h];
      s1[node * 8 + h * 2 + 1] = ay[h] / ad[h];
    }
  }
}

// ---------- fused node kernel: s1 -> relu(out1+bias1) -> xl2,xr2 ----------
__global__ void k_node1(const float* __restrict__ s1,
                        const float* __restrict__ Wl1, const float* __restrict__ bl1,
                        const float* __restrict__ bias1,
                        const float* __restrict__ Wl2, const float* __restrict__ bl2,
                        const float* __restrict__ Wr2, const float* __restrict__ br2,
                        float* __restrict__ xl2, float* __restrict__ xr2) {
  __shared__ float t[16][256];
  int tid = threadIdx.x;
  int base = blockIdx.x * 16;
  int h = tid >> 6;
  float w0 = Wl1[tid * 2], w1 = Wl1[tid * 2 + 1], bb = bl1[tid] + bias1[tid];
  for (int i = 0; i < 16; i++) {
    int node = base + i;
    float s0 = s1[node * 8 + h * 2], sv = s1[node * 8 + h * 2 + 1];
    float v = w0 * s0 + w1 * sv + bb;
    t[i][tid] = v > 0.f ? v : 0.f;
  }
  __syncthreads();
  int ch = tid & 127;
  int grp = tid >> 7;
  const float* W = (ch < 64) ? (Wl2 + ch * 256) : (Wr2 + (ch - 64) * 256);
  float bias = (ch < 64) ? bl2[ch] : br2[ch - 64];
  float acc[8];
#pragma unroll
  for (int n = 0; n < 8; n++) acc[n] = bias;
  for (int k = 0; k < 256; k += 4) {
    float4 w4 = *(const float4*)(W + k);
#pragma unroll
    for (int n = 0; n < 8; n++) {
      const float* tp = &t[grp * 8 + n][k];
      acc[n] += w4.x * tp[0] + w4.y * tp[1] + w4.z * tp[2] + w4.w * tp[3];
    }
  }
#pragma unroll
  for (int n = 0; n < 8; n++) {
    int node = base + grp * 8 + n;
    if (ch < 64) xl2[node * 64 + ch] = acc[n];
    else         xr2[node * 64 + (ch - 64)] = acc[n];
  }
}

// ---------- conv2: fused logits+softmax+agg, wave per dst node ----------
__global__ __launch_bounds__(256) void k_conv2(
    const float* __restrict__ xl2, const float* __restrict__ xr2,
    const int* __restrict__ rowptr, const int* __restrict__ csr_src,
    const float* __restrict__ att2, float* __restrict__ out2) {
  int lane = threadIdx.x & 63;
  int node = blockIdx.x * 4 + (threadIdx.x >> 6);
  if (node >= NN) return;
  float xr = xr2[node * 64 + lane];
  float at = att2[lane];
  float num = 0.f, den = 0.f;
  int start = rowptr[node], end = rowptr[node + 1];
  int j = start;
  for (; j + 1 < end; j += 2) {
    int s0 = csr_src[j], s1v = csr_src[j + 1];
    float xl0 = xl2[s0 * 64 + lane];
    float xl1 = xl2[s1v * 64 + lane];
    float v0 = leaky(xl0 + xr) * at;
    float v1 = leaky(xl1 + xr) * at;
#pragma unroll
    for (int off = 1; off <= 32; off <<= 1) {
      v0 += __shfl_xor(v0, off, 64);
      v1 += __shfl_xor(v1, off, 64);
    }
    float e0 = __expf(v0), e1 = __expf(v1);
    num += e0 * xl0 + e1 * xl1;
    den += e0 + e1;
  }
  if (j < end) {
    int s0 = csr_src[j];
    float xl0 = xl2[s0 * 64 + lane];
    float v0 = leaky(xl0 + xr) * at;
#pragma unroll
    for (int off = 1; off <= 32; off <<= 1) v0 += __shfl_xor(v0, off, 64);
    float e0 = __expf(v0);
    num += e0 * xl0;
    den += e0;
  }
  out2[node * 64 + lane] = num / den;
}

// ---------- pooling: wave per 32 contiguous nodes (batch sorted) ----------
__global__ void k_pool(const float* __restrict__ out2, const int* __restrict__ batch,
                       float* __restrict__ pool, float* __restrict__ counts) {
  int lane = threadIdx.x & 63;
  int wid = blockIdx.x * 4 + (threadIdx.x >> 6);
  int start = wid * 32;
  if (start >= NN) return;
  int end = start + 32; if (end > NN) end = NN;
  int cur = batch[start];
  float acc = 0.f; int cnt = 0;
  for (int node = start; node < end; node++) {
    int b = batch[node];
    if (b != cur) {
      atomicAdd(&pool[cur * 64 + lane], acc);
      if (lane == 0) atomicAdd(&counts[cur], (float)cnt);
      acc = 0.f; cnt = 0; cur = b;
    }
    acc += out2[node * 64 + lane];
    cnt++;
  }
  atomicAdd(&pool[cur * 64 + lane], acc);
  if (lane == 0) atomicAdd(&counts[cur], (float)cnt);
}

// ---------- final: mean + MLP, one block per graph, LDS activations ----------
__global__ void k_final(const float* __restrict__ pool, const float* __restrict__ counts,
                        const float* __restrict__ bias2, const float* __restrict__ bk,
                        const float* __restrict__ wc1, const float* __restrict__ bc1,
                        const float* __restrict__ wc2, const float* __restrict__ bc2,
                        const float* __restrict__ wc3, const float* __restrict__ bc3,
                        float* __restrict__ out) {
  __shared__ float sge[65], sc1[32], sc2[16];
  int g = blockIdx.x, t = threadIdx.x;
  if (t < 64) {
    float cnt = counts[g]; cnt = cnt > 1.f ? cnt : 1.f;
    sge[t] = pool[g * 64 + t] / cnt + bias2[t];
  }
  if (t == 0) sge[64] = bk[g];
  __syncthreads();
  if (t < 32) {
    float a = bc1[t];
    for (int k = 0; k < 65; k++) a += wc1[t * 65 + k] * sge[k];
    sc1[t] = a > 0.f ? a : 0.f;
  }
  __syncthreads();
  if (t < 16) {
    float a = bc2[t];
    for (int k = 0; k < 32; k++) a += wc2[t * 32 + k] * sc1[k];
    sc2[t] = a > 0.f ? a : 0.f;
  }
  __syncthreads();
  if (t == 0) {
    float a = bc3[0];
    for (int k = 0; k < 16; k++) a += wc3[k] * sc2[k];
    out[g] = bk[g] + a;
  }
}

extern "C" void kernel_launch(void* const* d_in, const int* in_sizes, int n_in,
                              void* d_out, int out_size, void* d_ws, size_t ws_size,
                              hipStream_t stream) {
  (void)in_sizes; (void)n_in; (void)out_size; (void)ws_size;
  const float* x     = (const float*)d_in[0];
  const int*   ei    = (const int*)d_in[1];
  const int*   batch = (const int*)d_in[2];
  const float* bk    = (const float*)d_in[3];
  const float* Wl1   = (const float*)d_in[4];
  const float* bl1   = (const float*)d_in[5];
  const float* Wr1   = (const float*)d_in[6];
  const float* br1   = (const float*)d_in[7];
  const float* att1  = (const float*)d_in[8];
  const float* bias1 = (const float*)d_in[9];
  const float* Wl2   = (const float*)d_in[10];
  const float* bl2   = (const float*)d_in[11];
  const float* Wr2   = (const float*)d_in[12];
  const float* br2   = (const float*)d_in[13];
  const float* att2  = (const float*)d_in[14];
  const float* bias2 = (const float*)d_in[15];
  const float* wc1   = (const float*)d_in[16];
  const float* bc1   = (const float*)d_in[17];
  const float* wc2   = (const float*)d_in[18];
  const float* bc2   = (const float*)d_in[19];
  const float* wc3   = (const float*)d_in[20];
  const float* bc3   = (const float*)d_in[21];
  float* out = (float*)d_out;

  float* ws = (float*)d_ws;
  // ---- zeroed region: [0, 54160) ----
  int*   deg     = (int*)(ws + 0);        // [N]      50000
  float* pool    = ws + 50000;            // [G*64]   4096
  float* cnts    = ws + 54096;            // [G]      64
  // ---- write-before-read region ----
  int*   rowptr  = (int*)(ws + 54160);    // [N+1]    50001 (+pad)
  int*   cursor  = (int*)(ws + 104164);   // [N]      50000
  int*   csr_src = (int*)(ws + 154164);   // [NT]     850000
  float* s1      = ws + 1004164;          // [N*4*2]  400000
  float* xl2     = ws + 1404164;          // [N*64]   3200000
  float* xr2     = ws + 4604164;          // [N*64]   3200000
  float* out2    = ws + 7804164;          // [N*64]   3200000

  hipMemsetAsync(ws, 0, 54160 * sizeof(float), stream);

  int eb = (NT + 255) / 256;
  k_hist<<<eb, 256, 0, stream>>>(ei, deg);
  k_scan<<<1, 1024, 0, stream>>>(deg, rowptr, cursor);
  k_scatter<<<eb, 256, 0, stream>>>(ei, cursor, csr_src);

  k_conv1<<<NN / 4, 256, 0, stream>>>(x, rowptr, csr_src, Wl1, bl1, Wr1, br1, att1, s1);
  k_node1<<<NN / 16, 256, 0, stream>>>(s1, Wl1, bl1, bias1, Wl2, bl2, Wr2, br2, xl2, xr2);
  k_conv2<<<NN / 4, 256, 0, stream>>>(xl2, xr2, rowptr, csr_src, att2, out2);

  k_pool<<<(((NN + 31) / 32) + 3) / 4, 256, 0, stream>>>(out2, batch, pool, cnts);
  k_final<<<NG, 64, 0, stream>>>(pool, cnts, bias2, bk, wc1, bc1, wc2, bc2, wc3, bc3, out);
}

// Round 4
// 437.524 us; speedup vs baseline: 2.5587x; 1.1876x over previous
//
#include <hip/hip_runtime.h>

#define NN 50000
#define NE 800000
#define NT (NE + NN)   /* 850000 edges incl self-loops */
#define NG 64

typedef __attribute__((ext_vector_type(8))) short short8;
typedef __attribute__((ext_vector_type(4))) float f32x4;

__device__ __forceinline__ float leaky(float v) { return v > 0.f ? v : 0.2f * v; }

__device__ __forceinline__ short f2bf(float f) {
  unsigned u = __float_as_uint(f);
  unsigned r = (u + 0x7fffu + ((u >> 16) & 1u)) >> 16;
  return (short)r;
}

// ---------- CSR build ----------
__global__ void k_hist(const int* __restrict__ ei, int* __restrict__ deg) {
  int e = blockIdx.x * 256 + threadIdx.x;
  if (e >= NT) return;
  int dst = (e < NE) ? ei[NE + e] : e - NE;
  atomicAdd(&deg[dst], 1);
}

__global__ __launch_bounds__(1024) void k_scan(const int* __restrict__ deg,
                                               int* __restrict__ rowptr,
                                               int* __restrict__ cursor) {
  __shared__ int part[1024];
  int t = threadIdx.x;
  const int CH = (NN + 1023) / 1024;  // 49
  int base = t * CH;
  int s = 0;
  for (int i = 0; i < CH; i++) {
    int idx = base + i;
    if (idx < NN) s += deg[idx];
  }
  part[t] = s;
  __syncthreads();
  for (int off = 1; off < 1024; off <<= 1) {
    int v = (t >= off) ? part[t - off] : 0;
    __syncthreads();
    part[t] += v;
    __syncthreads();
  }
  int run = (t == 0) ? 0 : part[t - 1];
  for (int i = 0; i < CH; i++) {
    int idx = base + i;
    if (idx < NN) {
      rowptr[idx] = run;
      cursor[idx] = run;
      run += deg[idx];
    }
  }
  if (t == 1023) rowptr[NN] = run;  // == NT
}

__global__ void k_scatter(const int* __restrict__ ei, int* __restrict__ cursor,
                          int* __restrict__ csr_src) {
  int e = blockIdx.x * 256 + threadIdx.x;
  if (e >= NT) return;
  int src, dst;
  if (e < NE) { src = ei[e]; dst = ei[NE + e]; } else { src = dst = e - NE; }
  int pos = atomicAdd(&cursor[dst], 1);
  csr_src[pos] = src;
}

// ---------- conv1: fused logits+softmax+agg, wave per dst node ----------
__global__ __launch_bounds__(256) void k_conv1(
    const float* __restrict__ x, const int* __restrict__ rowptr,
    const int* __restrict__ csr_src,
    const float* __restrict__ Wl1, const float* __restrict__ bl1,
    const float* __restrict__ Wr1, const float* __restrict__ br1,
    const float* __restrict__ att1, float* __restrict__ s1) {
  int lane = threadIdx.x & 63;
  int node = blockIdx.x * 4 + (threadIdx.x >> 6);
  if (node >= NN) return;
  int sub = lane & 15, grp = lane >> 4;
  const float2* x2 = (const float2*)x;
  float2 xd = x2[node];
  float wl0[4][4], wl1r[4][4], r[4][4], at[4][4];
#pragma unroll
  for (int h = 0; h < 4; h++)
#pragma unroll
    for (int k = 0; k < 4; k++) {
      int ch = h * 64 + sub * 4 + k;
      wl0[h][k] = Wl1[ch * 2];
      wl1r[h][k] = Wl1[ch * 2 + 1];
      r[h][k] = Wr1[ch * 2] * xd.x + Wr1[ch * 2 + 1] * xd.y + bl1[ch] + br1[ch];
      at[h][k] = att1[ch];
    }
  float ax[4] = {0, 0, 0, 0}, ay[4] = {0, 0, 0, 0}, ad[4] = {0, 0, 0, 0};
  int start = rowptr[node], end = rowptr[node + 1];
  for (int j = start; j < end; j += 4) {
    int e = j + grp;
    bool valid = e < end;
    int src = valid ? csr_src[e] : node;
    float2 xs = x2[src];
    float p[4];
#pragma unroll
    for (int h = 0; h < 4; h++) {
      float a = 0.f;
#pragma unroll
      for (int k = 0; k < 4; k++) {
        float v = wl0[h][k] * xs.x + wl1r[h][k] * xs.y + r[h][k];
        a += at[h][k] * leaky(v);
      }
      p[h] = a;
    }
#pragma unroll
    for (int off = 1; off <= 8; off <<= 1) {
#pragma unroll
      for (int h = 0; h < 4; h++) p[h] += __shfl_xor(p[h], off, 64);
    }
#pragma unroll
    for (int h = 0; h < 4; h++) {
      float exv = valid ? __expf(p[h]) : 0.f;
      ax[h] += exv * xs.x;
      ay[h] += exv * xs.y;
      ad[h] += exv;
    }
  }
#pragma unroll
  for (int off = 16; off <= 32; off <<= 1) {
#pragma unroll
    for (int h = 0; h < 4; h++) {
      ax[h] += __shfl_xor(ax[h], off, 64);
      ay[h] += __shfl_xor(ay[h], off, 64);
      ad[h] += __shfl_xor(ad[h], off, 64);
    }
  }
  if (lane == 0) {
#pragma unroll
    for (int h = 0; h < 4; h++) {
      s1[node * 8 + h * 2 + 0] = ax[h] / ad[h];
      s1[node * 8 + h * 2 + 1] = ay[h] / ad[h];
    }
  }
}

// ---------- prep: Wl2||Wr2 -> bf16, pre-arranged in MFMA B-fragment order ----------
// B[k][n] = W[n][k].  Fragment (nt, ks): lane l holds n = nt*16+(l&15),
// k = ks*32 + (l>>4)*8 + j, j=0..7.  Flat: (((nt*8+ks)*64 + l)<<3) + j
__global__ void k_prep(const float* __restrict__ Wl2, const float* __restrict__ Wr2,
                       short* __restrict__ Wb) {
  int idx = blockIdx.x * 256 + threadIdx.x;  // 128*256 elems
  int n = idx >> 8, k = idx & 255;
  float v = (n < 64) ? Wl2[n * 256 + k] : Wr2[(n - 64) * 256 + k];
  int nt = n >> 4, ks = k >> 5;
  int l = (n & 15) + (((k >> 3) & 3) << 4);
  int j = k & 7;
  Wb[(((nt * 8 + ks) * 64 + l) << 3) + j] = f2bf(v);
}

// ---------- node1 via MFMA: s1 -> t=relu(.) bf16 in LDS -> [64x256]@[256x128] ----------
#define TPAD 264  /* bf16 row stride: 528 B, dword stride 132 == 4 mod 32 */
__global__ __launch_bounds__(256) void k_node1(
    const float* __restrict__ s1,
    const float* __restrict__ Wl1, const float* __restrict__ bl1,
    const float* __restrict__ bias1,
    const short* __restrict__ Wb,
    const float* __restrict__ bl2, const float* __restrict__ br2,
    float* __restrict__ xl2, float* __restrict__ xr2) {
  __shared__ short t_lds[64 * TPAD];
  __shared__ float s_lds[512];
  int tid = threadIdx.x;
  int base = blockIdx.x * 64;

  // stage s1[base..base+64)[8] -> s_lds
  {
    int g0 = base * 8;
    if (g0 + 512 <= NN * 8) {
      if (tid < 128) {
        float4 v = *(const float4*)(s1 + g0 + tid * 4);
        *(float4*)(s_lds + tid * 4) = v;
      }
    } else {
      for (int i = tid; i < 512; i += 256) {
        int g = g0 + i;
        s_lds[i] = (g < NN * 8) ? s1[g] : 0.f;
      }
    }
  }
  __syncthreads();

  // phase 1: t[node][ch] = relu(w0*s0 + w1*s1 + bl1 + bias1), ch = tid
  {
    int ch = tid, h = tid >> 6;
    float w0 = Wl1[ch * 2], w1 = Wl1[ch * 2 + 1], bb = bl1[ch] + bias1[ch];
    for (int i = 0; i < 64; i++) {
      float s0 = s_lds[i * 8 + h * 2], sv = s_lds[i * 8 + h * 2 + 1];
      float v = w0 * s0 + w1 * sv + bb;
      t_lds[i * TPAD + ch] = f2bf(v > 0.f ? v : 0.f);
    }
  }
  __syncthreads();

  // phase 2: MFMA.  wave w: rows [w*16, w*16+16); 8 N-tiles of 16; K=256
  int lane = tid & 63, w = tid >> 6;
  int row = w * 16 + (lane & 15);
  const short8* wb8 = (const short8*)Wb;
  f32x4 acc[8];
#pragma unroll
  for (int nt = 0; nt < 8; nt++) {
    int ch = nt * 16 + (lane & 15);
    float b = (ch < 64) ? bl2[ch] : br2[ch - 64];
    acc[nt] = (f32x4){b, b, b, b};
  }
#pragma unroll
  for (int ks = 0; ks < 8; ks++) {
    short8 a = *(const short8*)&t_lds[row * TPAD + ks * 32 + (lane >> 4) * 8];
#pragma unroll
    for (int nt = 0; nt < 8; nt++) {
      short8 bfr = wb8[(nt * 8 + ks) * 64 + lane];
      acc[nt] = __builtin_amdgcn_mfma_f32_16x16x32_bf16(a, bfr, acc[nt], 0, 0, 0);
    }
  }
  // store: D col = lane&15 (channel), row = (lane>>4)*4 + reg (node)
#pragma unroll
  for (int nt = 0; nt < 8; nt++) {
    int ch = nt * 16 + (lane & 15);
#pragma unroll
    for (int r = 0; r < 4; r++) {
      int node = base + w * 16 + (lane >> 4) * 4 + r;
      if (node < NN) {
        if (nt < 4) xl2[node * 64 + ch] = acc[nt][r];
        else        xr2[node * 64 + (ch - 64)] = acc[nt][r];
      }
    }
  }
}

// ---------- conv2: fused logits+softmax+agg, wave per dst node ----------
__global__ __launch_bounds__(256) void k_conv2(
    const float* __restrict__ xl2, const float* __restrict__ xr2,
    const int* __restrict__ rowptr, const int* __restrict__ csr_src,
    const float* __restrict__ att2, float* __restrict__ out2) {
  int lane = threadIdx.x & 63;
  int node = blockIdx.x * 4 + (threadIdx.x >> 6);
  if (node >= NN) return;
  float xr = xr2[node * 64 + lane];
  float at = att2[lane];
  float num = 0.f, den = 0.f;
  int start = rowptr[node], end = rowptr[node + 1];
  int j = start;
  for (; j + 1 < end; j += 2) {
    int s0 = csr_src[j], s1v = csr_src[j + 1];
    float xl0 = xl2[s0 * 64 + lane];
    float xl1 = xl2[s1v * 64 + lane];
    float v0 = leaky(xl0 + xr) * at;
    float v1 = leaky(xl1 + xr) * at;
#pragma unroll
    for (int off = 1; off <= 32; off <<= 1) {
      v0 += __shfl_xor(v0, off, 64);
      v1 += __shfl_xor(v1, off, 64);
    }
    float e0 = __expf(v0), e1 = __expf(v1);
    num += e0 * xl0 + e1 * xl1;
    den += e0 + e1;
  }
  if (j < end) {
    int s0 = csr_src[j];
    float xl0 = xl2[s0 * 64 + lane];
    float v0 = leaky(xl0 + xr) * at;
#pragma unroll
    for (int off = 1; off <= 32; off <<= 1) v0 += __shfl_xor(v0, off, 64);
    float e0 = __expf(v0);
    num += e0 * xl0;
    den += e0;
  }
  out2[node * 64 + lane] = num / den;
}

// ---------- pooling: wave per 32 contiguous nodes (batch sorted) ----------
__global__ void k_pool(const float* __restrict__ out2, const int* __restrict__ batch,
                       float* __restrict__ pool, float* __restrict__ counts) {
  int lane = threadIdx.x & 63;
  int wid = blockIdx.x * 4 + (threadIdx.x >> 6);
  int start = wid * 32;
  if (start >= NN) return;
  int end = start + 32; if (end > NN) end = NN;
  int cur = batch[start];
  float acc = 0.f; int cnt = 0;
  for (int node = start; node < end; node++) {
    int b = batch[node];
    if (b != cur) {
      atomicAdd(&pool[cur * 64 + lane], acc);
      if (lane == 0) atomicAdd(&counts[cur], (float)cnt);
      acc = 0.f; cnt = 0; cur = b;
    }
    acc += out2[node * 64 + lane];
    cnt++;
  }
  atomicAdd(&pool[cur * 64 + lane], acc);
  if (lane == 0) atomicAdd(&counts[cur], (float)cnt);
}

// ---------- final: mean + MLP, one block per graph, LDS activations ----------
__global__ void k_final(const float* __restrict__ pool, const float* __restrict__ counts,
                        const float* __restrict__ bias2, const float* __restrict__ bk,
                        const float* __restrict__ wc1, const float* __restrict__ bc1,
                        const float* __restrict__ wc2, const float* __restrict__ bc2,
                        const float* __restrict__ wc3, const float* __restrict__ bc3,
                        float* __restrict__ out) {
  __shared__ float sge[65], sc1[32], sc2[16];
  int g = blockIdx.x, t = threadIdx.x;
  if (t < 64) {
    float cnt = counts[g]; cnt = cnt > 1.f ? cnt : 1.f;
    sge[t] = pool[g * 64 + t] / cnt + bias2[t];
  }
  if (t == 0) sge[64] = bk[g];
  __syncthreads();
  if (t < 32) {
    float a = bc1[t];
    for (int k = 0; k < 65; k++) a += wc1[t * 65 + k] * sge[k];
    sc1[t] = a > 0.f ? a : 0.f;
  }
  __syncthreads();
  if (t < 16) {
    float a = bc2[t];
    for (int k = 0; k < 32; k++) a += wc2[t * 32 + k] * sc1[k];
    sc2[t] = a > 0.f ? a : 0.f;
  }
  __syncthreads();
  if (t == 0) {
    float a = bc3[0];
    for (int k = 0; k < 16; k++) a += wc3[k] * sc2[k];
    out[g] = bk[g] + a;
  }
}

extern "C" void kernel_launch(void* const* d_in, const int* in_sizes, int n_in,
                              void* d_out, int out_size, void* d_ws, size_t ws_size,
                              hipStream_t stream) {
  (void)in_sizes; (void)n_in; (void)out_size; (void)ws_size;
  const float* x     = (const float*)d_in[0];
  const int*   ei    = (const int*)d_in[1];
  const int*   batch = (const int*)d_in[2];
  const float* bk    = (const float*)d_in[3];
  const float* Wl1   = (const float*)d_in[4];
  const float* bl1   = (const float*)d_in[5];
  const float* Wr1   = (const float*)d_in[6];
  const float* br1   = (const float*)d_in[7];
  const float* att1  = (const float*)d_in[8];
  const float* bias1 = (const float*)d_in[9];
  const float* Wl2   = (const float*)d_in[10];
  const float* bl2   = (const float*)d_in[11];
  const float* Wr2   = (const float*)d_in[12];
  const float* br2   = (const float*)d_in[13];
  const float* att2  = (const float*)d_in[14];
  const float* bias2 = (const float*)d_in[15];
  const float* wc1   = (const float*)d_in[16];
  const float* bc1   = (const float*)d_in[17];
  const float* wc2   = (const float*)d_in[18];
  const float* bc2   = (const float*)d_in[19];
  const float* wc3   = (const float*)d_in[20];
  const float* bc3   = (const float*)d_in[21];
  float* out = (float*)d_out;

  float* ws = (float*)d_ws;
  // ---- zeroed region: [0, 54160) ----
  int*   deg     = (int*)(ws + 0);        // [N]      50000
  float* pool    = ws + 50000;            // [G*64]   4096
  float* cnts    = ws + 54096;            // [G]      64
  // ---- write-before-read region ----
  int*   rowptr  = (int*)(ws + 54160);    // [N+1]    50001 (+pad)
  int*   cursor  = (int*)(ws + 104164);   // [N]      50000
  int*   csr_src = (int*)(ws + 154164);   // [NT]     850000
  float* s1      = ws + 1004164;          // [N*4*2]  400000
  float* xl2     = ws + 1404164;          // [N*64]   3200000
  float* xr2     = ws + 4604164;          // [N*64]   3200000
  float* out2    = ws + 7804164;          // [N*64]   3200000
  short* Wb      = (short*)(ws + 11004164); // [128*256] bf16 (16384 floats)

  hipMemsetAsync(ws, 0, 54160 * sizeof(float), stream);

  int eb = (NT + 255) / 256;
  k_hist<<<eb, 256, 0, stream>>>(ei, deg);
  k_prep<<<128, 256, 0, stream>>>(Wl2, Wr2, Wb);
  k_scan<<<1, 1024, 0, stream>>>(deg, rowptr, cursor);
  k_scatter<<<eb, 256, 0, stream>>>(ei, cursor, csr_src);

  k_conv1<<<NN / 4, 256, 0, stream>>>(x, rowptr, csr_src, Wl1, bl1, Wr1, br1, att1, s1);
  k_node1<<<(NN + 63) / 64, 256, 0, stream>>>(s1, Wl1, bl1, bias1, Wb, bl2, br2, xl2, xr2);
  k_conv2<<<NN / 4, 256, 0, stream>>>(xl2, xr2, rowptr, csr_src, att2, out2);

  k_pool<<<(((NN + 31) / 32) + 3) / 4, 256, 0, stream>>>(out2, batch, pool, cnts);
  k_final<<<NG, 64, 0, stream>>>(pool, cnts, bias2, bk, wc1, bc1, wc2, bc2, wc3, bc3, out);
}

// Round 5
// 322.942 us; speedup vs baseline: 3.4666x; 1.3548x over previous
//
#include <hip/hip_runtime.h>

#define NN 50000
#define NE 800000
#define NT (NE + NN)   /* 850000 edges incl self-loops */
#define NG 64
#define NB 49          /* scan blocks: 49*1024 >= NN */

typedef __attribute__((ext_vector_type(8))) short short8;
typedef __attribute__((ext_vector_type(4))) float f32x4;

__device__ __forceinline__ float leaky(float v) { return v > 0.f ? v : 0.2f * v; }

__device__ __forceinline__ short f2bf(float f) {
  unsigned u = __float_as_uint(f);
  unsigned r = (u + 0x7fffu + ((u >> 16) & 1u)) >> 16;
  return (short)r;
}

// ---------- CSR build ----------
__global__ void k_hist(const int* __restrict__ ei, int* __restrict__ deg) {
  int e = blockIdx.x * 256 + threadIdx.x;
  if (e >= NT) return;
  int dst = (e < NE) ? ei[NE + e] : e - NE;
  atomicAdd(&deg[dst], 1);
}

// two-level scan: block sums -> scan of sums -> per-block scan
__global__ __launch_bounds__(256) void k_scan1(const int* __restrict__ deg,
                                               int* __restrict__ bsum) {
  int b = blockIdx.x, t = threadIdx.x;
  int base = b * 1024 + t * 4;
  int s = 0;
  if (base + 3 < NN) {
    int4 v = *(const int4*)(deg + base);
    s = v.x + v.y + v.z + v.w;
  } else {
#pragma unroll
    for (int k = 0; k < 4; k++) if (base + k < NN) s += deg[base + k];
  }
#pragma unroll
  for (int off = 1; off < 64; off <<= 1) s += __shfl_xor(s, off, 64);
  __shared__ int ws[4];
  if ((t & 63) == 0) ws[t >> 6] = s;
  __syncthreads();
  if (t == 0) bsum[b] = ws[0] + ws[1] + ws[2] + ws[3];
}

__global__ void k_scan2(const int* __restrict__ bsum, int* __restrict__ boff) {
  int t = threadIdx.x;  // 64
  int v = (t < NB) ? bsum[t] : 0;
  int incl = v;
#pragma unroll
  for (int off = 1; off < 64; off <<= 1) {
    int u = __shfl_up(incl, off, 64);
    if (t >= off) incl += u;
  }
  if (t < NB) boff[t] = incl - v;
}

__global__ __launch_bounds__(256) void k_scan3(const int* __restrict__ deg,
                                               const int* __restrict__ boff,
                                               int* __restrict__ rowptr,
                                               int* __restrict__ cursor) {
  __shared__ int wsum[4];
  int b = blockIdx.x, t = threadIdx.x;
  int lane = t & 63, w = t >> 6;
  int base = b * 1024 + t * 4;
  int d0 = 0, d1 = 0, d2 = 0, d3 = 0;
  if (base + 3 < NN) {
    int4 v = *(const int4*)(deg + base);
    d0 = v.x; d1 = v.y; d2 = v.z; d3 = v.w;
  } else {
    if (base + 0 < NN) d0 = deg[base + 0];
    if (base + 1 < NN) d1 = deg[base + 1];
    if (base + 2 < NN) d2 = deg[base + 2];
    if (base + 3 < NN) d3 = deg[base + 3];
  }
  int s = d0 + d1 + d2 + d3;
  int incl = s;
#pragma unroll
  for (int off = 1; off < 64; off <<= 1) {
    int u = __shfl_up(incl, off, 64);
    if (lane >= off) incl += u;
  }
  if (lane == 63) wsum[w] = incl;
  __syncthreads();
  int woff = 0;
  for (int i = 0; i < w; i++) woff += wsum[i];
  int e0 = boff[b] + woff + incl - s;
  int e1 = e0 + d0, e2 = e1 + d1, e3 = e2 + d2;
  if (base + 0 < NN) { rowptr[base + 0] = e0; cursor[base + 0] = e0; if (base + 0 == NN - 1) rowptr[NN] = e0 + d0; }
  if (base + 1 < NN) { rowptr[base + 1] = e1; cursor[base + 1] = e1; if (base + 1 == NN - 1) rowptr[NN] = e1 + d1; }
  if (base + 2 < NN) { rowptr[base + 2] = e2; cursor[base + 2] = e2; if (base + 2 == NN - 1) rowptr[NN] = e2 + d2; }
  if (base + 3 < NN) { rowptr[base + 3] = e3; cursor[base + 3] = e3; if (base + 3 == NN - 1) rowptr[NN] = e3 + d3; }
}

__global__ void k_scatter(const int* __restrict__ ei, int* __restrict__ cursor,
                          int* __restrict__ csr_src) {
  int e = blockIdx.x * 256 + threadIdx.x;
  if (e >= NT) return;
  int src, dst;
  if (e < NE) { src = ei[e]; dst = ei[NE + e]; } else { src = dst = e - NE; }
  int pos = atomicAdd(&cursor[dst], 1);
  csr_src[pos] = src;
}

// ---------- conv1: fused logits+softmax+agg, wave per dst node ----------
__global__ __launch_bounds__(256) void k_conv1(
    const float* __restrict__ x, const int* __restrict__ rowptr,
    const int* __restrict__ csr_src,
    const float* __restrict__ Wl1, const float* __restrict__ bl1,
    const float* __restrict__ Wr1, const float* __restrict__ br1,
    const float* __restrict__ att1, float* __restrict__ s1) {
  int lane = threadIdx.x & 63;
  int node = blockIdx.x * 4 + (threadIdx.x >> 6);
  if (node >= NN) return;
  int sub = lane & 15, grp = lane >> 4;
  const float2* x2 = (const float2*)x;
  float2 xd = x2[node];
  float wl0[4][4], wl1r[4][4], r[4][4], at[4][4];
#pragma unroll
  for (int h = 0; h < 4; h++)
#pragma unroll
    for (int k = 0; k < 4; k++) {
      int ch = h * 64 + sub * 4 + k;
      wl0[h][k] = Wl1[ch * 2];
      wl1r[h][k] = Wl1[ch * 2 + 1];
      r[h][k] = Wr1[ch * 2] * xd.x + Wr1[ch * 2 + 1] * xd.y + bl1[ch] + br1[ch];
      at[h][k] = att1[ch];
    }
  float ax[4] = {0, 0, 0, 0}, ay[4] = {0, 0, 0, 0}, ad[4] = {0, 0, 0, 0};
  int start = rowptr[node], end = rowptr[node + 1];
  for (int j = start; j < end; j += 4) {
    int e = j + grp;
    bool valid = e < end;
    int src = valid ? csr_src[e] : node;
    float2 xs = x2[src];
    float p[4];
#pragma unroll
    for (int h = 0; h < 4; h++) {
      float a = 0.f;
#pragma unroll
      for (int k = 0; k < 4; k++) {
        float v = wl0[h][k] * xs.x + wl1r[h][k] * xs.y + r[h][k];
        a += at[h][k] * leaky(v);
      }
      p[h] = a;
    }
#pragma unroll
    for (int off = 1; off <= 8; off <<= 1) {
#pragma unroll
      for (int h = 0; h < 4; h++) p[h] += __shfl_xor(p[h], off, 64);
    }
#pragma unroll
    for (int h = 0; h < 4; h++) {
      float exv = valid ? __expf(p[h]) : 0.f;
      ax[h] += exv * xs.x;
      ay[h] += exv * xs.y;
      ad[h] += exv;
    }
  }
#pragma unroll
  for (int off = 16; off <= 32; off <<= 1) {
#pragma unroll
    for (int h = 0; h < 4; h++) {
      ax[h] += __shfl_xor(ax[h], off, 64);
      ay[h] += __shfl_xor(ay[h], off, 64);
      ad[h] += __shfl_xor(ad[h], off, 64);
    }
  }
  if (lane == 0) {
#pragma unroll
    for (int h = 0; h < 4; h++) {
      s1[node * 8 + h * 2 + 0] = ax[h] / ad[h];
      s1[node * 8 + h * 2 + 1] = ay[h] / ad[h];
    }
  }
}

// ---------- prep: Wl2||Wr2 -> bf16, pre-arranged in MFMA B-fragment order ----------
__global__ void k_prep(const float* __restrict__ Wl2, const float* __restrict__ Wr2,
                       short* __restrict__ Wb) {
  int idx = blockIdx.x * 256 + threadIdx.x;  // 128*256 elems
  int n = idx >> 8, k = idx & 255;
  float v = (n < 64) ? Wl2[n * 256 + k] : Wr2[(n - 64) * 256 + k];
  int nt = n >> 4, ks = k >> 5;
  int l = (n & 15) + (((k >> 3) & 3) << 4);
  int j = k & 7;
  Wb[(((nt * 8 + ks) * 64 + l) << 3) + j] = f2bf(v);
}

// ---------- node1 via MFMA: s1 -> t=relu(.) bf16 in LDS -> [64x256]@[256x128] ----------
#define TPAD 264  /* bf16 row stride: 528 B, dword stride 132 == 4 mod 32 */
__global__ __launch_bounds__(256) void k_node1(
    const float* __restrict__ s1,
    const float* __restrict__ Wl1, const float* __restrict__ bl1,
    const float* __restrict__ bias1,
    const short* __restrict__ Wb,
    const float* __restrict__ bl2, const float* __restrict__ br2,
    float* __restrict__ xl2, float* __restrict__ xr2) {
  __shared__ short t_lds[64 * TPAD];
  __shared__ float s_lds[512];
  int tid = threadIdx.x;
  int base = blockIdx.x * 64;

  {
    int g0 = base * 8;
    if (g0 + 512 <= NN * 8) {
      if (tid < 128) {
        float4 v = *(const float4*)(s1 + g0 + tid * 4);
        *(float4*)(s_lds + tid * 4) = v;
      }
    } else {
      for (int i = tid; i < 512; i += 256) {
        int g = g0 + i;
        s_lds[i] = (g < NN * 8) ? s1[g] : 0.f;
      }
    }
  }
  __syncthreads();

  {
    int ch = tid, h = tid >> 6;
    float w0 = Wl1[ch * 2], w1 = Wl1[ch * 2 + 1], bb = bl1[ch] + bias1[ch];
    for (int i = 0; i < 64; i++) {
      float s0 = s_lds[i * 8 + h * 2], sv = s_lds[i * 8 + h * 2 + 1];
      float v = w0 * s0 + w1 * sv + bb;
      t_lds[i * TPAD + ch] = f2bf(v > 0.f ? v : 0.f);
    }
  }
  __syncthreads();

  int lane = tid & 63, w = tid >> 6;
  int row = w * 16 + (lane & 15);
  const short8* wb8 = (const short8*)Wb;
  f32x4 acc[8];
#pragma unroll
  for (int nt = 0; nt < 8; nt++) {
    int ch = nt * 16 + (lane & 15);
    float b = (ch < 64) ? bl2[ch] : br2[ch - 64];
    acc[nt] = (f32x4){b, b, b, b};
  }
#pragma unroll
  for (int ks = 0; ks < 8; ks++) {
    short8 a = *(const short8*)&t_lds[row * TPAD + ks * 32 + (lane >> 4) * 8];
#pragma unroll
    for (int nt = 0; nt < 8; nt++) {
      short8 bfr = wb8[(nt * 8 + ks) * 64 + lane];
      acc[nt] = __builtin_amdgcn_mfma_f32_16x16x32_bf16(a, bfr, acc[nt], 0, 0, 0);
    }
  }
#pragma unroll
  for (int nt = 0; nt < 8; nt++) {
    int ch = nt * 16 + (lane & 15);
#pragma unroll
    for (int r = 0; r < 4; r++) {
      int node = base + w * 16 + (lane >> 4) * 4 + r;
      if (node < NN) {
        if (nt < 4) xl2[node * 64 + ch] = acc[nt][r];
        else        xr2[node * 64 + (ch - 64)] = acc[nt][r];
      }
    }
  }
}

// ---------- conv2: fused logits+softmax+agg, wave per dst node ----------
__global__ __launch_bounds__(256) void k_conv2(
    const float* __restrict__ xl2, const float* __restrict__ xr2,
    const int* __restrict__ rowptr, const int* __restrict__ csr_src,
    const float* __restrict__ att2, float* __restrict__ out2) {
  int lane = threadIdx.x & 63;
  int node = blockIdx.x * 4 + (threadIdx.x >> 6);
  if (node >= NN) return;
  float xr = xr2[node * 64 + lane];
  float at = att2[lane];
  float num = 0.f, den = 0.f;
  int start = rowptr[node], end = rowptr[node + 1];
  int j = start;
  for (; j + 1 < end; j += 2) {
    int s0 = csr_src[j], s1v = csr_src[j + 1];
    float xl0 = xl2[s0 * 64 + lane];
    float xl1 = xl2[s1v * 64 + lane];
    float v0 = leaky(xl0 + xr) * at;
    float v1 = leaky(xl1 + xr) * at;
#pragma unroll
    for (int off = 1; off <= 32; off <<= 1) {
      v0 += __shfl_xor(v0, off, 64);
      v1 += __shfl_xor(v1, off, 64);
    }
    float e0 = __expf(v0), e1 = __expf(v1);
    num += e0 * xl0 + e1 * xl1;
    den += e0 + e1;
  }
  if (j < end) {
    int s0 = csr_src[j];
    float xl0 = xl2[s0 * 64 + lane];
    float v0 = leaky(xl0 + xr) * at;
#pragma unroll
    for (int off = 1; off <= 32; off <<= 1) v0 += __shfl_xor(v0, off, 64);
    float e0 = __expf(v0);
    num += e0 * xl0;
    den += e0;
  }
  out2[node * 64 + lane] = num / den;
}

// ---------- pooling: wave per 32 contiguous nodes (batch sorted) ----------
__global__ void k_pool(const float* __restrict__ out2, const int* __restrict__ batch,
                       float* __restrict__ pool, float* __restrict__ counts) {
  int lane = threadIdx.x & 63;
  int wid = blockIdx.x * 4 + (threadIdx.x >> 6);
  int start = wid * 32;
  if (start >= NN) return;
  int end = start + 32; if (end > NN) end = NN;
  int cur = batch[start];
  float acc = 0.f; int cnt = 0;
  for (int node = start; node < end; node++) {
    int b = batch[node];
    if (b != cur) {
      atomicAdd(&pool[cur * 64 + lane], acc);
      if (lane == 0) atomicAdd(&counts[cur], (float)cnt);
      acc = 0.f; cnt = 0; cur = b;
    }
    acc += out2[node * 64 + lane];
    cnt++;
  }
  atomicAdd(&pool[cur * 64 + lane], acc);
  if (lane == 0) atomicAdd(&counts[cur], (float)cnt);
}

// ---------- final: mean + MLP, one block per graph, LDS activations ----------
__global__ void k_final(const float* __restrict__ pool, const float* __restrict__ counts,
                        const float* __restrict__ bias2, const float* __restrict__ bk,
                        const float* __restrict__ wc1, const float* __restrict__ bc1,
                        const float* __restrict__ wc2, const float* __restrict__ bc2,
                        const float* __restrict__ wc3, const float* __restrict__ bc3,
                        float* __restrict__ out) {
  __shared__ float sge[65], sc1[32], sc2[16];
  int g = blockIdx.x, t = threadIdx.x;
  if (t < 64) {
    float cnt = counts[g]; cnt = cnt > 1.f ? cnt : 1.f;
    sge[t] = pool[g * 64 + t] / cnt + bias2[t];
  }
  if (t == 0) sge[64] = bk[g];
  __syncthreads();
  if (t < 32) {
    float a = bc1[t];
    for (int k = 0; k < 65; k++) a += wc1[t * 65 + k] * sge[k];
    sc1[t] = a > 0.f ? a : 0.f;
  }
  __syncthreads();
  if (t < 16) {
    float a = bc2[t];
    for (int k = 0; k < 32; k++) a += wc2[t * 32 + k] * sc1[k];
    sc2[t] = a > 0.f ? a : 0.f;
  }
  __syncthreads();
  if (t == 0) {
    float a = bc3[0];
    for (int k = 0; k < 16; k++) a += wc3[k] * sc2[k];
    out[g] = bk[g] + a;
  }
}

extern "C" void kernel_launch(void* const* d_in, const int* in_sizes, int n_in,
                              void* d_out, int out_size, void* d_ws, size_t ws_size,
                              hipStream_t stream) {
  (void)in_sizes; (void)n_in; (void)out_size; (void)ws_size;
  const float* x     = (const float*)d_in[0];
  const int*   ei    = (const int*)d_in[1];
  const int*   batch = (const int*)d_in[2];
  const float* bk    = (const float*)d_in[3];
  const float* Wl1   = (const float*)d_in[4];
  const float* bl1   = (const float*)d_in[5];
  const float* Wr1   = (const float*)d_in[6];
  const float* br1   = (const float*)d_in[7];
  const float* att1  = (const float*)d_in[8];
  const float* bias1 = (const float*)d_in[9];
  const float* Wl2   = (const float*)d_in[10];
  const float* bl2   = (const float*)d_in[11];
  const float* Wr2   = (const float*)d_in[12];
  const float* br2   = (const float*)d_in[13];
  const float* att2  = (const float*)d_in[14];
  const float* bias2 = (const float*)d_in[15];
  const float* wc1   = (const float*)d_in[16];
  const float* bc1   = (const float*)d_in[17];
  const float* wc2   = (const float*)d_in[18];
  const float* bc2   = (const float*)d_in[19];
  const float* wc3   = (const float*)d_in[20];
  const float* bc3   = (const float*)d_in[21];
  float* out = (float*)d_out;

  float* ws = (float*)d_ws;
  // ---- zeroed region: [0, 54160) ----
  int*   deg     = (int*)(ws + 0);        // [N]      50000
  float* pool    = ws + 50000;            // [G*64]   4096
  float* cnts    = ws + 54096;            // [G]      64
  // ---- write-before-read region ----
  int*   rowptr  = (int*)(ws + 54160);    // [N+1]    50001 (+pad)
  int*   cursor  = (int*)(ws + 104164);   // [N]      50000
  int*   csr_src = (int*)(ws + 154164);   // [NT]     850000
  float* s1      = ws + 1004164;          // [N*4*2]  400000
  float* xl2     = ws + 1404164;          // [N*64]   3200000
  float* xr2     = ws + 4604164;          // [N*64]   3200000
  float* out2    = ws + 7804164;          // [N*64]   3200000
  short* Wb      = (short*)(ws + 11004164); // [128*256] bf16 (16384 floats)
  int*   bsum    = (int*)(ws + 11020548); // [64]
  int*   boff    = (int*)(ws + 11020612); // [64]

  hipMemsetAsync(ws, 0, 54160 * sizeof(float), stream);

  int eb = (NT + 255) / 256;
  k_hist<<<eb, 256, 0, stream>>>(ei, deg);
  k_prep<<<128, 256, 0, stream>>>(Wl2, Wr2, Wb);
  k_scan1<<<NB, 256, 0, stream>>>(deg, bsum);
  k_scan2<<<1, 64, 0, stream>>>(bsum, boff);
  k_scan3<<<NB, 256, 0, stream>>>(deg, boff, rowptr, cursor);
  k_scatter<<<eb, 256, 0, stream>>>(ei, cursor, csr_src);

  k_conv1<<<NN / 4, 256, 0, stream>>>(x, rowptr, csr_src, Wl1, bl1, Wr1, br1, att1, s1);
  k_node1<<<(NN + 63) / 64, 256, 0, stream>>>(s1, Wl1, bl1, bias1, Wb, bl2, br2, xl2, xr2);
  k_conv2<<<NN / 4, 256, 0, stream>>>(xl2, xr2, rowptr, csr_src, att2, out2);

  k_pool<<<(((NN + 31) / 32) + 3) / 4, 256, 0, stream>>>(out2, batch, pool, cnts);
  k_final<<<NG, 64, 0, stream>>>(pool, cnts, bias2, bk, wc1, bc1, wc2, bc2, wc3, bc3, out);
}

// Round 6
// 260.479 us; speedup vs baseline: 4.2978x; 1.2398x over previous
//
#include <hip/hip_runtime.h>

#define NN 50000
#define NE 800000
#define NT (NE + NN)   /* 850000 edges incl self-loops */
#define NG 64
#define NB 49          /* scan blocks: 49*1024 >= NN */

typedef __attribute__((ext_vector_type(8))) short short8;
typedef __attribute__((ext_vector_type(4))) float f32x4;
typedef __attribute__((ext_vector_type(2))) float f32x2;

__device__ __forceinline__ float leaky(float v) { return fmaxf(v, 0.2f * v); }

__device__ __forceinline__ short f2bf(float f) {
  unsigned u = __float_as_uint(f);
  unsigned r = (u + 0x7fffu + ((u >> 16) & 1u)) >> 16;
  return (short)r;
}

// ---------- CSR build ----------
__global__ void k_hist(const int* __restrict__ ei, int* __restrict__ deg) {
  int e = blockIdx.x * 256 + threadIdx.x;
  if (e >= NT) return;
  int dst = (e < NE) ? ei[NE + e] : e - NE;
  atomicAdd(&deg[dst], 1);
}

__global__ __launch_bounds__(256) void k_scan1(const int* __restrict__ deg,
                                               int* __restrict__ bsum) {
  int b = blockIdx.x, t = threadIdx.x;
  int base = b * 1024 + t * 4;
  int s = 0;
  if (base + 3 < NN) {
    int4 v = *(const int4*)(deg + base);
    s = v.x + v.y + v.z + v.w;
  } else {
#pragma unroll
    for (int k = 0; k < 4; k++) if (base + k < NN) s += deg[base + k];
  }
#pragma unroll
  for (int off = 1; off < 64; off <<= 1) s += __shfl_xor(s, off, 64);
  __shared__ int ws[4];
  if ((t & 63) == 0) ws[t >> 6] = s;
  __syncthreads();
  if (t == 0) bsum[b] = ws[0] + ws[1] + ws[2] + ws[3];
}

__global__ void k_scan2(const int* __restrict__ bsum, int* __restrict__ boff) {
  int t = threadIdx.x;  // 64
  int v = (t < NB) ? bsum[t] : 0;
  int incl = v;
#pragma unroll
  for (int off = 1; off < 64; off <<= 1) {
    int u = __shfl_up(incl, off, 64);
    if (t >= off) incl += u;
  }
  if (t < NB) boff[t] = incl - v;
}

__global__ __launch_bounds__(256) void k_scan3(const int* __restrict__ deg,
                                               const int* __restrict__ boff,
                                               int* __restrict__ rowptr,
                                               int* __restrict__ cursor) {
  __shared__ int wsum[4];
  int b = blockIdx.x, t = threadIdx.x;
  int lane = t & 63, w = t >> 6;
  int base = b * 1024 + t * 4;
  int d0 = 0, d1 = 0, d2 = 0, d3 = 0;
  if (base + 3 < NN) {
    int4 v = *(const int4*)(deg + base);
    d0 = v.x; d1 = v.y; d2 = v.z; d3 = v.w;
  } else {
    if (base + 0 < NN) d0 = deg[base + 0];
    if (base + 1 < NN) d1 = deg[base + 1];
    if (base + 2 < NN) d2 = deg[base + 2];
    if (base + 3 < NN) d3 = deg[base + 3];
  }
  int s = d0 + d1 + d2 + d3;
  int incl = s;
#pragma unroll
  for (int off = 1; off < 64; off <<= 1) {
    int u = __shfl_up(incl, off, 64);
    if (lane >= off) incl += u;
  }
  if (lane == 63) wsum[w] = incl;
  __syncthreads();
  int woff = 0;
  for (int i = 0; i < w; i++) woff += wsum[i];
  int e0 = boff[b] + woff + incl - s;
  int e1 = e0 + d0, e2 = e1 + d1, e3 = e2 + d2;
  if (base + 0 < NN) { rowptr[base + 0] = e0; cursor[base + 0] = e0; if (base + 0 == NN - 1) rowptr[NN] = e0 + d0; }
  if (base + 1 < NN) { rowptr[base + 1] = e1; cursor[base + 1] = e1; if (base + 1 == NN - 1) rowptr[NN] = e1 + d1; }
  if (base + 2 < NN) { rowptr[base + 2] = e2; cursor[base + 2] = e2; if (base + 2 == NN - 1) rowptr[NN] = e2 + d2; }
  if (base + 3 < NN) { rowptr[base + 3] = e3; cursor[base + 3] = e3; if (base + 3 == NN - 1) rowptr[NN] = e3 + d3; }
}

__global__ void k_scatter(const int* __restrict__ ei, int* __restrict__ cursor,
                          int* __restrict__ csr_src) {
  int e = blockIdx.x * 256 + threadIdx.x;
  if (e >= NT) return;
  int src, dst;
  if (e < NE) { src = ei[e]; dst = ei[NE + e]; } else { src = dst = e - NE; }
  int pos = atomicAdd(&cursor[dst], 1);
  csr_src[pos] = src;
}

// ---------- conv1: fused logits+softmax+agg, wave per dst node ----------
// chunk-load 64 edges; 4 edges/iter; 16 lanes per edge; reduce-scatter
__global__ __launch_bounds__(256) void k_conv1(
    const float* __restrict__ x, const int* __restrict__ rowptr,
    const int* __restrict__ csr_src,
    const float* __restrict__ Wl1, const float* __restrict__ bl1,
    const float* __restrict__ Wr1, const float* __restrict__ br1,
    const float* __restrict__ att1, float* __restrict__ s1) {
  int lane = threadIdx.x & 63;
  int node = blockIdx.x * 4 + (threadIdx.x >> 6);
  if (node >= NN) return;
  int sub = lane & 15, grp = lane >> 4;
  const float2* x2 = (const float2*)x;
  float2 xd = x2[node];
  // this lane's 16 channels as 8 f32x2 pairs: ch = h*64 + sub*4 + 2p + {0,1}
  f32x2 A0[4][2], A1[4][2], R[4][2], AT[4][2];
#pragma unroll
  for (int h = 0; h < 4; h++)
#pragma unroll
    for (int p = 0; p < 2; p++) {
      int c0 = h * 64 + sub * 4 + 2 * p;
      A0[h][p] = (f32x2){Wl1[c0 * 2], Wl1[(c0 + 1) * 2]};
      A1[h][p] = (f32x2){Wl1[c0 * 2 + 1], Wl1[(c0 + 1) * 2 + 1]};
      R[h][p]  = (f32x2){Wr1[c0 * 2] * xd.x + Wr1[c0 * 2 + 1] * xd.y + bl1[c0] + br1[c0],
                         Wr1[(c0 + 1) * 2] * xd.x + Wr1[(c0 + 1) * 2 + 1] * xd.y + bl1[c0 + 1] + br1[c0 + 1]};
      AT[h][p] = (f32x2){att1[c0], att1[c0 + 1]};
    }
  float ax = 0.f, ay = 0.f, ad = 0.f;
  int start = rowptr[node], end = rowptr[node + 1];
  for (int cb = start; cb < end; cb += 64) {
    int eL = cb + lane;
    int srcL = (eL < end) ? csr_src[eL] : node;
    float2 xsL = x2[srcL];
    int cnt = end - cb; if (cnt > 64) cnt = 64;
    for (int it = 0; it * 4 < cnt; it++) {
      int idx = it * 4 + grp;
      bool valid = idx < cnt;
      float xsx = __shfl(xsL.x, idx, 64);
      float xsy = __shfl(xsL.y, idx, 64);
      float lg[4];
#pragma unroll
      for (int h = 0; h < 4; h++) {
        f32x2 acc = (f32x2){0.f, 0.f};
#pragma unroll
        for (int p = 0; p < 2; p++) {
          f32x2 v = A0[h][p] * xsx + A1[h][p] * xsy + R[h][p];
          f32x2 lk;
          lk.x = fmaxf(v.x, 0.2f * v.x);
          lk.y = fmaxf(v.y, 0.2f * v.y);
          acc += AT[h][p] * lk;
        }
        lg[h] = acc.x + acc.y;
      }
      // reduce-scatter over sub bits 0-1, then butterfly bits 2-3
      float t0 = __shfl_xor(lg[0], 1, 64), t1 = __shfl_xor(lg[1], 1, 64);
      float t2 = __shfl_xor(lg[2], 1, 64), t3 = __shfl_xor(lg[3], 1, 64);
      float a0, a1;
      if (sub & 1) { a0 = lg[2] + t2; a1 = lg[3] + t3; }
      else         { a0 = lg[0] + t0; a1 = lg[1] + t1; }
      float u0 = __shfl_xor(a0, 2, 64), u1 = __shfl_xor(a1, 2, 64);
      float b = (sub & 2) ? (a1 + u1) : (a0 + u0);
      b += __shfl_xor(b, 4, 64);
      b += __shfl_xor(b, 8, 64);
      // lane holds head m = ((sub&1)<<1)|((sub>>1)&1), replicated over sub>>2
      float e = valid ? __expf(b) : 0.f;
      ad += e; ax += e * xsx; ay += e * xsy;
    }
  }
  // combine across the 4 groups (same sub => same head role)
  ax += __shfl_xor(ax, 16, 64); ax += __shfl_xor(ax, 32, 64);
  ay += __shfl_xor(ay, 16, 64); ay += __shfl_xor(ay, 32, 64);
  ad += __shfl_xor(ad, 16, 64); ad += __shfl_xor(ad, 32, 64);
  if (lane < 4) {
    int h = ((sub & 1) << 1) | ((sub >> 1) & 1);
    s1[node * 8 + h * 2 + 0] = ax / ad;
    s1[node * 8 + h * 2 + 1] = ay / ad;
  }
}

// ---------- prep: Wl2||Wr2 -> bf16, pre-arranged in MFMA B-fragment order ----------
__global__ void k_prep(const float* __restrict__ Wl2, const float* __restrict__ Wr2,
                       short* __restrict__ Wb) {
  int idx = blockIdx.x * 256 + threadIdx.x;  // 128*256 elems
  int n = idx >> 8, k = idx & 255;
  float v = (n < 64) ? Wl2[n * 256 + k] : Wr2[(n - 64) * 256 + k];
  int nt = n >> 4, ks = k >> 5;
  int l = (n & 15) + (((k >> 3) & 3) << 4);
  int j = k & 7;
  Wb[(((nt * 8 + ks) * 64 + l) << 3) + j] = f2bf(v);
}

// ---------- node1 via MFMA: s1 -> t=relu(.) bf16 in LDS -> [64x256]@[256x128] ----------
#define TPAD 264  /* bf16 row stride: 528 B, dword stride 132 == 4 mod 32 */
__global__ __launch_bounds__(256) void k_node1(
    const float* __restrict__ s1,
    const float* __restrict__ Wl1, const float* __restrict__ bl1,
    const float* __restrict__ bias1,
    const short* __restrict__ Wb,
    const float* __restrict__ bl2, const float* __restrict__ br2,
    float* __restrict__ xl2, float* __restrict__ xr2) {
  __shared__ short t_lds[64 * TPAD];
  __shared__ float s_lds[512];
  int tid = threadIdx.x;
  int base = blockIdx.x * 64;

  {
    int g0 = base * 8;
    if (g0 + 512 <= NN * 8) {
      if (tid < 128) {
        float4 v = *(const float4*)(s1 + g0 + tid * 4);
        *(float4*)(s_lds + tid * 4) = v;
      }
    } else {
      for (int i = tid; i < 512; i += 256) {
        int g = g0 + i;
        s_lds[i] = (g < NN * 8) ? s1[g] : 0.f;
      }
    }
  }
  __syncthreads();

  {
    int ch = tid, h = tid >> 6;
    float w0 = Wl1[ch * 2], w1 = Wl1[ch * 2 + 1], bb = bl1[ch] + bias1[ch];
    for (int i = 0; i < 64; i++) {
      float s0 = s_lds[i * 8 + h * 2], sv = s_lds[i * 8 + h * 2 + 1];
      float v = w0 * s0 + w1 * sv + bb;
      t_lds[i * TPAD + ch] = f2bf(v > 0.f ? v : 0.f);
    }
  }
  __syncthreads();

  int lane = tid & 63, w = tid >> 6;
  int row = w * 16 + (lane & 15);
  const short8* wb8 = (const short8*)Wb;
  f32x4 acc[8];
#pragma unroll
  for (int nt = 0; nt < 8; nt++) {
    int ch = nt * 16 + (lane & 15);
    float b = (ch < 64) ? bl2[ch] : br2[ch - 64];
    acc[nt] = (f32x4){b, b, b, b};
  }
#pragma unroll
  for (int ks = 0; ks < 8; ks++) {
    short8 a = *(const short8*)&t_lds[row * TPAD + ks * 32 + (lane >> 4) * 8];
#pragma unroll
    for (int nt = 0; nt < 8; nt++) {
      short8 bfr = wb8[(nt * 8 + ks) * 64 + lane];
      acc[nt] = __builtin_amdgcn_mfma_f32_16x16x32_bf16(a, bfr, acc[nt], 0, 0, 0);
    }
  }
#pragma unroll
  for (int nt = 0; nt < 8; nt++) {
    int ch = nt * 16 + (lane & 15);
#pragma unroll
    for (int r = 0; r < 4; r++) {
      int node = base + w * 16 + (lane >> 4) * 4 + r;
      if (node < NN) {
        if (nt < 4) xl2[node * 64 + ch] = acc[nt][r];
        else        xr2[node * 64 + (ch - 64)] = acc[nt][r];
      }
    }
  }
}

// ---------- conv2: fused logits+softmax+agg, wave per dst node ----------
// chunk-load 64 srcs; 4 edges/iter; 16 lanes x float4 per edge
__global__ __launch_bounds__(256) void k_conv2(
    const float* __restrict__ xl2, const float* __restrict__ xr2,
    const int* __restrict__ rowptr, const int* __restrict__ csr_src,
    const float* __restrict__ att2, float* __restrict__ out2) {
  int lane = threadIdx.x & 63;
  int node = blockIdx.x * 4 + (threadIdx.x >> 6);
  if (node >= NN) return;
  int sub = lane & 15, grp = lane >> 4;
  float4 xr = *(const float4*)(xr2 + node * 64 + sub * 4);
  float4 at = *(const float4*)(att2 + sub * 4);
  float4 num = {0.f, 0.f, 0.f, 0.f};
  float den = 0.f;
  int start = rowptr[node], end = rowptr[node + 1];
  for (int cb = start; cb < end; cb += 64) {
    int eL = cb + lane;
    int srcL = (eL < end) ? csr_src[eL] : node;
    int cnt = end - cb; if (cnt > 64) cnt = 64;
    for (int it = 0; it * 4 < cnt; it++) {
      int idx = it * 4 + grp;
      bool valid = idx < cnt;
      int src = __shfl(srcL, idx, 64);
      float4 xl = *(const float4*)(xl2 + src * 64 + sub * 4);
      float v = at.x * leaky(xl.x + xr.x) + at.y * leaky(xl.y + xr.y)
              + at.z * leaky(xl.z + xr.z) + at.w * leaky(xl.w + xr.w);
      v += __shfl_xor(v, 1, 64);
      v += __shfl_xor(v, 2, 64);
      v += __shfl_xor(v, 4, 64);
      v += __shfl_xor(v, 8, 64);
      float e = valid ? __expf(v) : 0.f;
      num.x += e * xl.x; num.y += e * xl.y; num.z += e * xl.z; num.w += e * xl.w;
      den += e;
    }
  }
#pragma unroll
  for (int off = 16; off <= 32; off <<= 1) {
    num.x += __shfl_xor(num.x, off, 64);
    num.y += __shfl_xor(num.y, off, 64);
    num.z += __shfl_xor(num.z, off, 64);
    num.w += __shfl_xor(num.w, off, 64);
    den   += __shfl_xor(den, off, 64);
  }
  if (grp == 0) {
    float4 o = {num.x / den, num.y / den, num.z / den, num.w / den};
    *(float4*)(out2 + node * 64 + sub * 4) = o;
  }
}

// ---------- pooling: wave per 32 contiguous nodes (batch sorted) ----------
__global__ void k_pool(const float* __restrict__ out2, const int* __restrict__ batch,
                       float* __restrict__ pool, float* __restrict__ counts) {
  int lane = threadIdx.x & 63;
  int wid = blockIdx.x * 4 + (threadIdx.x >> 6);
  int start = wid * 32;
  if (start >= NN) return;
  int end = start + 32; if (end > NN) end = NN;
  int cur = batch[start];
  float acc = 0.f; int cnt = 0;
  for (int node = start; node < end; node++) {
    int b = batch[node];
    if (b != cur) {
      atomicAdd(&pool[cur * 64 + lane], acc);
      if (lane == 0) atomicAdd(&counts[cur], (float)cnt);
      acc = 0.f; cnt = 0; cur = b;
    }
    acc += out2[node * 64 + lane];
    cnt++;
  }
  atomicAdd(&pool[cur * 64 + lane], acc);
  if (lane == 0) atomicAdd(&counts[cur], (float)cnt);
}

// ---------- final: mean + MLP, one block per graph, LDS activations ----------
__global__ void k_final(const float* __restrict__ pool, const float* __restrict__ counts,
                        const float* __restrict__ bias2, const float* __restrict__ bk,
                        const float* __restrict__ wc1, const float* __restrict__ bc1,
                        const float* __restrict__ wc2, const float* __restrict__ bc2,
                        const float* __restrict__ wc3, const float* __restrict__ bc3,
                        float* __restrict__ out) {
  __shared__ float sge[65], sc1[32], sc2[16];
  int g = blockIdx.x, t = threadIdx.x;
  if (t < 64) {
    float cnt = counts[g]; cnt = cnt > 1.f ? cnt : 1.f;
    sge[t] = pool[g * 64 + t] / cnt + bias2[t];
  }
  if (t == 0) sge[64] = bk[g];
  __syncthreads();
  if (t < 32) {
    float a = bc1[t];
    for (int k = 0; k < 65; k++) a += wc1[t * 65 + k] * sge[k];
    sc1[t] = a > 0.f ? a : 0.f;
  }
  __syncthreads();
  if (t < 16) {
    float a = bc2[t];
    for (int k = 0; k < 32; k++) a += wc2[t * 32 + k] * sc1[k];
    sc2[t] = a > 0.f ? a : 0.f;
  }
  __syncthreads();
  if (t == 0) {
    float a = bc3[0];
    for (int k = 0; k < 16; k++) a += wc3[k] * sc2[k];
    out[g] = bk[g] + a;
  }
}

extern "C" void kernel_launch(void* const* d_in, const int* in_sizes, int n_in,
                              void* d_out, int out_size, void* d_ws, size_t ws_size,
                              hipStream_t stream) {
  (void)in_sizes; (void)n_in; (void)out_size; (void)ws_size;
  const float* x     = (const float*)d_in[0];
  const int*   ei    = (const int*)d_in[1];
  const int*   batch = (const int*)d_in[2];
  const float* bk    = (const float*)d_in[3];
  const float* Wl1   = (const float*)d_in[4];
  const float* bl1   = (const float*)d_in[5];
  const float* Wr1   = (const float*)d_in[6];
  const float* br1   = (const float*)d_in[7];
  const float* att1  = (const float*)d_in[8];
  const float* bias1 = (const float*)d_in[9];
  const float* Wl2   = (const float*)d_in[10];
  const float* bl2   = (const float*)d_in[11];
  const float* Wr2   = (const float*)d_in[12];
  const float* br2   = (const float*)d_in[13];
  const float* att2  = (const float*)d_in[14];
  const float* bias2 = (const float*)d_in[15];
  const float* wc1   = (const float*)d_in[16];
  const float* bc1   = (const float*)d_in[17];
  const float* wc2   = (const float*)d_in[18];
  const float* bc2   = (const float*)d_in[19];
  const float* wc3   = (const float*)d_in[20];
  const float* bc3   = (const float*)d_in[21];
  float* out = (float*)d_out;

  float* ws = (float*)d_ws;
  // ---- zeroed region: [0, 54160) ----
  int*   deg     = (int*)(ws + 0);        // [N]      50000
  float* pool    = ws + 50000;            // [G*64]   4096
  float* cnts    = ws + 54096;            // [G]      64
  // ---- write-before-read region ----
  int*   rowptr  = (int*)(ws + 54160);    // [N+1]    50001 (+pad)
  int*   cursor  = (int*)(ws + 104164);   // [N]      50000
  int*   csr_src = (int*)(ws + 154164);   // [NT]     850000
  float* s1      = ws + 1004164;          // [N*4*2]  400000
  float* xl2     = ws + 1404164;          // [N*64]   3200000
  float* xr2     = ws + 4604164;          // [N*64]   3200000
  float* out2    = ws + 7804164;          // [N*64]   3200000
  short* Wb      = (short*)(ws + 11004164); // [128*256] bf16 (16384 floats)
  int*   bsum    = (int*)(ws + 11020548); // [64]
  int*   boff    = (int*)(ws + 11020612); // [64]

  hipMemsetAsync(ws, 0, 54160 * sizeof(float), stream);

  int eb = (NT + 255) / 256;
  k_hist<<<eb, 256, 0, stream>>>(ei, deg);
  k_prep<<<128, 256, 0, stream>>>(Wl2, Wr2, Wb);
  k_scan1<<<NB, 256, 0, stream>>>(deg, bsum);
  k_scan2<<<1, 64, 0, stream>>>(bsum, boff);
  k_scan3<<<NB, 256, 0, stream>>>(deg, boff, rowptr, cursor);
  k_scatter<<<eb, 256, 0, stream>>>(ei, cursor, csr_src);

  k_conv1<<<NN / 4, 256, 0, stream>>>(x, rowptr, csr_src, Wl1, bl1, Wr1, br1, att1, s1);
  k_node1<<<(NN + 63) / 64, 256, 0, stream>>>(s1, Wl1, bl1, bias1, Wb, bl2, br2, xl2, xr2);
  k_conv2<<<NN / 4, 256, 0, stream>>>(xl2, xr2, rowptr, csr_src, att2, out2);

  k_pool<<<(((NN + 31) / 32) + 3) / 4, 256, 0, stream>>>(out2, batch, pool, cnts);
  k_final<<<NG, 64, 0, stream>>>(pool, cnts, bias2, bk, wc1, bc1, wc2, bc2, wc3, bc3, out);
}